// Round 1
// baseline (1099.624 us; speedup 1.0000x reference)
//
#include <hip/hip_runtime.h>
#include <cstdint>
#include <cstddef>

#define S_LEN 97
#define B_DIM 256
#define W_DIM 1024
#define NH    16
#define HDIM  64
#define MROWS (S_LEN * B_DIM)   // 24832 = 194*128

typedef unsigned short u16;
typedef __bf16 bf16x8 __attribute__((ext_vector_type(8)));
typedef float  f32x4  __attribute__((ext_vector_type(4)));

__device__ __forceinline__ u16 f2bf(float f) {
  union { float f; uint32_t u; } v; v.f = f;
  uint32_t u = v.u;
  return (u16)((u + 0x7FFFu + ((u >> 16) & 1u)) >> 16);  // RNE
}
__device__ __forceinline__ float bf2f(u16 h) {
  union { uint32_t u; float f; } v; v.u = ((uint32_t)h) << 16;
  return v.f;
}

// async global->LDS, 16B per lane. LDS dest must be wave-uniform base; HW adds lane*16.
__device__ __forceinline__ void gload16(const void* g, void* lds) {
  __builtin_amdgcn_global_load_lds(
      (const __attribute__((address_space(1))) void*)(uintptr_t)g,
      (__attribute__((address_space(3))) void*)(uint32_t)(uintptr_t)lds,
      16, 0, 0);
}

// ---------------- prep kernels ----------------
__global__ void k_cvt(const float* __restrict__ s, u16* __restrict__ d, int n4) {
  int i = blockIdx.x * blockDim.x + threadIdx.x;
  if (i >= n4) return;
  float4 v = ((const float4*)s)[i];
  u16 o0 = f2bf(v.x), o1 = f2bf(v.y), o2 = f2bf(v.z), o3 = f2bf(v.w);
  uint2 pk;
  pk.x = (uint32_t)o0 | ((uint32_t)o1 << 16);
  pk.y = (uint32_t)o2 | ((uint32_t)o3 << 16);
  ((uint2*)d)[i] = pk;
}

__global__ void k_bias3(const float* a, const float* b, const float* c, float* dst) {
  int i = blockIdx.x * blockDim.x + threadIdx.x;
  if (i >= 3 * W_DIM) return;
  if (i < W_DIM) dst[i] = a[i];
  else if (i < 2 * W_DIM) dst[i] = b[i - W_DIM];
  else dst[i] = c[i - 2 * W_DIM];
}

__global__ void k_rope_tab(float* __restrict__ tab) {
  int idx = blockIdx.x * blockDim.x + threadIdx.x;
  if (idx >= S_LEN * 512) return;
  int s = idx / 512, i = idx % 512;
  // inv_freq = 10000^(-i/512)
  float freq = expf(-(float)i * (9.210340371976184f / 512.0f));
  float ang = (float)s * freq;
  float sv, cv;
  sincosf(ang, &sv, &cv);
  tab[idx * 2 + 0] = cv;
  tab[idx * 2 + 1] = sv;
}

// in-place rotary on cols [0,2048) of qkv1 (row stride 3072 bf16)
__global__ void k_rope(u16* __restrict__ qkv1, const float* __restrict__ tab) {
  int t = blockIdx.x * blockDim.x + threadIdx.x;
  const int total = MROWS * 512 * 2;
  if (t >= total) return;
  int z = t / (MROWS * 512);           // 0=q, 1=k
  int rem = t - z * (MROWS * 512);
  int r = rem >> 9;                    // row (s*256+b)
  int i = rem & 511;                   // pair index
  int s = r >> 8;
  uint32_t* p = (uint32_t*)qkv1 + (size_t)r * 1536 + z * 512 + i;
  uint32_t pv = *p;
  float xe = bf2f((u16)(pv & 0xffffu));
  float xo = bf2f((u16)(pv >> 16));
  float2 cs = ((const float2*)tab)[s * 512 + i];
  float oe = xe * cs.x - xo * cs.y;
  float oo = xe * cs.y + xo * cs.x;
  *p = (uint32_t)f2bf(oe) | ((uint32_t)f2bf(oo) << 16);
}

// ---------------- GEMM: C[M,N] = A[M,K] @ Bw[N,K]^T + bias ----------------
// OUT_MODE: 0 = bf16 row-major (ldc), 1 = qkv-heads bf16 layout, 2 = f32 row-major
// ACOLB: A column offset = (n0 & ~1023)  (block-diagonal second projection)
template <int OUT_MODE, int ACOLB>
__global__ __launch_bounds__(256) void k_gemm(
    const u16* __restrict__ A, int lda, const u16* __restrict__ Bw,
    const float* __restrict__ bias, void* __restrict__ Cp, int ldc, int K,
    size_t thirdStride) {
  __shared__ u16 As[128 * 64];
  __shared__ u16 Bs[128 * 64];

  const int tid = threadIdx.x, lane = tid & 63, wave = tid >> 6;
  const int wm = wave >> 1, wn = wave & 1;
  const int m0 = blockIdx.x * 128;
  const int n0 = blockIdx.y * 128;
  const int aoff = ACOLB ? (n0 & ~1023) : 0;

  f32x4 acc[4][4] = {};

  const int lrow = lane >> 3;          // 0..7
  const int lcol = (lane & 7) * 8;     // 0..56 (elements)
  const u16* Ag = A + (size_t)(m0 + wave * 8 + lrow) * lda + aoff + lcol;
  const u16* Bg = Bw + (size_t)(n0 + wave * 8 + lrow) * K + lcol;
  u16* Asl = As + wave * 8 * 64;
  u16* Bsl = Bs + wave * 8 * 64;

  for (int kt = 0; kt < K; kt += 64) {
#pragma unroll
    for (int i = 0; i < 4; ++i) {
      gload16(Ag + (size_t)(i * 32) * lda + kt, Asl + i * 2048);
      gload16(Bg + (size_t)(i * 32) * K + kt, Bsl + i * 2048);
    }
    __syncthreads();  // drains vmcnt -> staged data visible
#pragma unroll
    for (int kk = 0; kk < 2; ++kk) {
      bf16x8 af[4], bfr[4];
#pragma unroll
      for (int m = 0; m < 4; ++m)
        af[m] = *(const bf16x8*)(As + (wm * 64 + m * 16 + (lane & 15)) * 64 + kk * 32 + (lane >> 4) * 8);
#pragma unroll
      for (int n = 0; n < 4; ++n)
        bfr[n] = *(const bf16x8*)(Bs + (wn * 64 + n * 16 + (lane & 15)) * 64 + kk * 32 + (lane >> 4) * 8);
#pragma unroll
      for (int m = 0; m < 4; ++m)
#pragma unroll
        for (int n = 0; n < 4; ++n)
          acc[m][n] = __builtin_amdgcn_mfma_f32_16x16x32_bf16(af[m], bfr[n], acc[m][n], 0, 0, 0);
    }
    __syncthreads();
  }

  const int r0 = (lane >> 4) * 4;
  const int c0 = lane & 15;
#pragma unroll
  for (int m = 0; m < 4; ++m) {
#pragma unroll
    for (int n = 0; n < 4; ++n) {
      const int col = n0 + wn * 64 + n * 16 + c0;
      const float bv = bias[col];
#pragma unroll
      for (int r = 0; r < 4; ++r) {
        const int row = m0 + wm * 64 + m * 16 + r0 + r;
        const float v = acc[m][n][r] + bv;
        if (OUT_MODE == 0) {
          ((u16*)Cp)[(size_t)row * ldc + col] = f2bf(v);
        } else if (OUT_MODE == 2) {
          ((float*)Cp)[(size_t)row * ldc + col] = v;
        } else {
          const int which = col >> 10, c = col & 1023;
          const int h = c >> 6, d = c & 63;
          const int s = row >> 8, b = row & 255;
          ((u16*)Cp)[(size_t)which * thirdStride +
                     (((size_t)(b * NH + h) * S_LEN + s) * HDIM + d)] = f2bf(v);
        }
      }
    }
  }
}

// ---------------- attention: one block per (b,h) ----------------
#define SC_LD 132
__global__ __launch_bounds__(256) void k_attn(const u16* __restrict__ qkv2,
                                              const float* __restrict__ mask,
                                              u16* __restrict__ O1) {
  __shared__ u16 Qs[128 * 64];
  __shared__ u16 Ks[128 * 64];
  __shared__ u16 Vt[64 * 128];          // transposed V: Vt[d][s]
  __shared__ float Sc[128 * SC_LD];     // scores f32 (padded stride)
  __shared__ u16 Pb[128 * 128];         // exp(scores-max) bf16
  __shared__ float inv[128];

  const size_t TS = (size_t)MROWS * W_DIM;
  const int bh = blockIdx.x, b = bh >> 4, h = bh & 15;
  const int tid = threadIdx.x, lane = tid & 63, wave = tid >> 6;
  const int wm = wave >> 1, wn = wave & 1;

  const u16* Qg = qkv2 + (size_t)bh * S_LEN * HDIM;
  const u16* Kg = qkv2 + TS + (size_t)bh * S_LEN * HDIM;
  const u16* Vg = qkv2 + 2 * TS + (size_t)bh * S_LEN * HDIM;

  // load + zero-pad Q,K; V transposed into Vt
  for (int idx = tid; idx < 1024; idx += 256) {
    const int row = idx >> 3, c = (idx & 7) * 8;
    uint4 qv = make_uint4(0, 0, 0, 0), kv = qv, vv = qv;
    if (row < S_LEN) {
      qv = *(const uint4*)(Qg + (size_t)row * HDIM + c);
      kv = *(const uint4*)(Kg + (size_t)row * HDIM + c);
      vv = *(const uint4*)(Vg + (size_t)row * HDIM + c);
    }
    *(uint4*)(Qs + row * 64 + c) = qv;
    *(uint4*)(Ks + row * 64 + c) = kv;
    u16 tmp[8];
    *(uint4*)tmp = vv;
#pragma unroll
    for (int j = 0; j < 8; ++j) Vt[(c + j) * 128 + row] = tmp[j];
  }
  __syncthreads();

  // QK^T: each wave 64x64 quadrant
  {
    f32x4 acc[4][4] = {};
#pragma unroll
    for (int kk = 0; kk < 2; ++kk) {
      bf16x8 af[4], bfr[4];
#pragma unroll
      for (int m = 0; m < 4; ++m)
        af[m] = *(const bf16x8*)(Qs + (wm * 64 + m * 16 + (lane & 15)) * 64 + kk * 32 + (lane >> 4) * 8);
#pragma unroll
      for (int n = 0; n < 4; ++n)
        bfr[n] = *(const bf16x8*)(Ks + (wn * 64 + n * 16 + (lane & 15)) * 64 + kk * 32 + (lane >> 4) * 8);
#pragma unroll
      for (int m = 0; m < 4; ++m)
#pragma unroll
        for (int n = 0; n < 4; ++n)
          acc[m][n] = __builtin_amdgcn_mfma_f32_16x16x32_bf16(af[m], bfr[n], acc[m][n], 0, 0, 0);
    }
    const int r0 = (lane >> 4) * 4, c0 = lane & 15;
#pragma unroll
    for (int m = 0; m < 4; ++m)
#pragma unroll
      for (int n = 0; n < 4; ++n)
#pragma unroll
        for (int r = 0; r < 4; ++r) {
          const int row = wm * 64 + m * 16 + r0 + r;
          const int col = wn * 64 + n * 16 + c0;
          const float mv = (row < S_LEN && col < S_LEN) ? mask[row * S_LEN + col] : 0.f;
          Sc[row * SC_LD + col] = acc[m][n][r] * 0.125f + mv;
        }
  }
  __syncthreads();

  // softmax (row per thread)
  if (tid < S_LEN) {
    const int row = tid;
    float mx = -1e30f;
    for (int k = 0; k < S_LEN; ++k) mx = fmaxf(mx, Sc[row * SC_LD + k]);
    float sum = 0.f;
    for (int k = 0; k < S_LEN; ++k) {
      const float e = __expf(Sc[row * SC_LD + k] - mx);
      sum += e;
      Pb[row * 128 + k] = f2bf(e);
    }
    for (int k = S_LEN; k < 128; ++k) Pb[row * 128 + k] = 0;
    inv[row] = 1.0f / sum;
  } else if (tid < 128) {
    for (int k = 0; k < 128; ++k) Pb[tid * 128 + k] = 0;
  }
  __syncthreads();

  // PV: each wave 64(M) x 32(N)
  {
    f32x4 acc[4][2] = {};
#pragma unroll
    for (int kk = 0; kk < 4; ++kk) {
      bf16x8 af[4], bfr[2];
#pragma unroll
      for (int m = 0; m < 4; ++m)
        af[m] = *(const bf16x8*)(Pb + (wm * 64 + m * 16 + (lane & 15)) * 128 + kk * 32 + (lane >> 4) * 8);
#pragma unroll
      for (int n = 0; n < 2; ++n)
        bfr[n] = *(const bf16x8*)(Vt + (wn * 32 + n * 16 + (lane & 15)) * 128 + kk * 32 + (lane >> 4) * 8);
#pragma unroll
      for (int m = 0; m < 4; ++m)
#pragma unroll
        for (int n = 0; n < 2; ++n)
          acc[m][n] = __builtin_amdgcn_mfma_f32_16x16x32_bf16(af[m], bfr[n], acc[m][n], 0, 0, 0);
    }
    const int r0 = (lane >> 4) * 4, c0 = lane & 15;
#pragma unroll
    for (int m = 0; m < 4; ++m)
#pragma unroll
      for (int n = 0; n < 2; ++n)
#pragma unroll
        for (int r = 0; r < 4; ++r) {
          const int row = wm * 64 + m * 16 + r0 + r;  // s
          if (row < S_LEN) {
            const int d = wn * 32 + n * 16 + c0;
            const float v = acc[m][n][r] * inv[row];
            O1[((size_t)row * B_DIM + b) * W_DIM + h * HDIM + d] = f2bf(v);
          }
        }
  }
}

// ---------------- launcher ----------------
extern "C" void kernel_launch(void* const* d_in, const int* in_sizes, int n_in,
                              void* d_out, int out_size, void* d_ws, size_t ws_size,
                              hipStream_t stream) {
  (void)in_sizes; (void)n_in; (void)out_size; (void)ws_size;
  const float* tensor    = (const float*)d_in[0];
  const float* mask      = (const float*)d_in[1];
  const float* q_w       = (const float*)d_in[2];
  const float* q_b       = (const float*)d_in[3];
  const float* k_w       = (const float*)d_in[4];
  const float* k_b       = (const float*)d_in[5];
  const float* v_w       = (const float*)d_in[6];
  const float* v_b       = (const float*)d_in[7];
  const float* in_proj_w = (const float*)d_in[8];
  const float* in_proj_b = (const float*)d_in[9];
  const float* mha_w     = (const float*)d_in[10];
  const float* mha_b     = (const float*)d_in[11];
  const float* out_w     = (const float*)d_in[12];
  const float* out_b     = (const float*)d_in[13];

  char* ws = (char*)d_ws;
  size_t off = 0;
  auto alloc = [&](size_t bytes) {
    char* p = ws + off;
    off += (bytes + 255) & ~(size_t)255;
    return p;
  };

  float* tab = (float*)alloc((size_t)S_LEN * 512 * 2 * sizeof(float));
  u16* Xbf   = (u16*)alloc((size_t)MROWS * W_DIM * 2);       // reused as O1
  u16* qkv1  = (u16*)alloc((size_t)MROWS * 3 * W_DIM * 2);   // head reused as O2
  u16* qkv2  = (u16*)alloc((size_t)MROWS * 3 * W_DIM * 2);
  u16* WC1   = (u16*)alloc((size_t)3 * W_DIM * W_DIM * 2);
  u16* W2    = (u16*)alloc((size_t)3 * W_DIM * W_DIM * 2);
  u16* WM    = (u16*)alloc((size_t)W_DIM * W_DIM * 2);
  u16* WO    = (u16*)alloc((size_t)W_DIM * W_DIM * 2);
  float* bc1 = (float*)alloc(3 * W_DIM * sizeof(float));
  u16* O1 = Xbf;   // X dead after GEMM1
  u16* O2 = qkv1;  // qkv1 dead after GEMM2

  // prep
  k_rope_tab<<<dim3((S_LEN * 512 + 255) / 256), 256, 0, stream>>>(tab);
  k_cvt<<<dim3(MROWS * W_DIM / 4 / 256), 256, 0, stream>>>(tensor, Xbf, MROWS * W_DIM / 4);
  k_cvt<<<dim3(1024), 256, 0, stream>>>(q_w, WC1, 262144);
  k_cvt<<<dim3(1024), 256, 0, stream>>>(k_w, WC1 + 1048576, 262144);
  k_cvt<<<dim3(1024), 256, 0, stream>>>(v_w, WC1 + 2097152, 262144);
  k_cvt<<<dim3(3072), 256, 0, stream>>>(in_proj_w, W2, 786432);
  k_cvt<<<dim3(1024), 256, 0, stream>>>(mha_w, WM, 262144);
  k_cvt<<<dim3(1024), 256, 0, stream>>>(out_w, WO, 262144);
  k_bias3<<<dim3(12), 256, 0, stream>>>(q_b, k_b, v_b, bc1);

  // GEMM1: X @ [q_w;k_w;v_w]^T + bias -> qkv1 (24832 x 3072)
  k_gemm<0, 0><<<dim3(MROWS / 128, 3072 / 128), 256, 0, stream>>>(
      Xbf, W_DIM, WC1, bc1, qkv1, 3072, W_DIM, 0);

  // rotary in place on q,k columns
  k_rope<<<dim3(MROWS * 512 * 2 / 256), 256, 0, stream>>>(qkv1, tab);

  // GEMM2 (block-diagonal): qkv1 @ in_proj^T + in_proj_b -> qkv2 in (B,H,S,HD)
  k_gemm<1, 1><<<dim3(MROWS / 128, 3072 / 128), 256, 0, stream>>>(
      qkv1, 3072, W2, in_proj_b, qkv2, 0, W_DIM, (size_t)MROWS * W_DIM);

  // attention
  k_attn<<<dim3(B_DIM * NH), 256, 0, stream>>>(qkv2, mask, O1);

  // output projections
  k_gemm<0, 0><<<dim3(MROWS / 128, W_DIM / 128), 256, 0, stream>>>(
      O1, W_DIM, WM, mha_b, O2, W_DIM, W_DIM, 0);
  k_gemm<2, 0><<<dim3(MROWS / 128, W_DIM / 128), 256, 0, stream>>>(
      O2, W_DIM, WO, out_b, d_out, W_DIM, W_DIM, 0);
}

// Round 2
// 1001.105 us; speedup vs baseline: 1.0984x; 1.0984x over previous
//
#include <hip/hip_runtime.h>
#include <cstdint>
#include <cstddef>

#define S_LEN 97
#define B_DIM 256
#define W_DIM 1024
#define NH    16
#define HDIM  64
#define MROWS (S_LEN * B_DIM)   // 24832 = 194*128

typedef unsigned short u16;
typedef __bf16 bf16x8 __attribute__((ext_vector_type(8)));
typedef float  f32x4  __attribute__((ext_vector_type(4)));

__device__ __forceinline__ u16 f2bf(float f) {
  union { float f; uint32_t u; } v; v.f = f;
  uint32_t u = v.u;
  return (u16)((u + 0x7FFFu + ((u >> 16) & 1u)) >> 16);  // RNE
}
__device__ __forceinline__ float bf2f(u16 h) {
  union { uint32_t u; float f; } v; v.u = ((uint32_t)h) << 16;
  return v.f;
}

// async global->LDS, 16B per lane. LDS dest must be wave-uniform base; HW adds lane*16.
__device__ __forceinline__ void gload16(const void* g, void* lds) {
  __builtin_amdgcn_global_load_lds(
      (const __attribute__((address_space(1))) void*)(uintptr_t)g,
      (__attribute__((address_space(3))) void*)(uint32_t)(uintptr_t)lds,
      16, 0, 0);
}

// ---------------- prep kernels ----------------
__global__ void k_cvt(const float* __restrict__ s, u16* __restrict__ d, int n4) {
  int i = blockIdx.x * blockDim.x + threadIdx.x;
  if (i >= n4) return;
  float4 v = ((const float4*)s)[i];
  u16 o0 = f2bf(v.x), o1 = f2bf(v.y), o2 = f2bf(v.z), o3 = f2bf(v.w);
  uint2 pk;
  pk.x = (uint32_t)o0 | ((uint32_t)o1 << 16);
  pk.y = (uint32_t)o2 | ((uint32_t)o3 << 16);
  ((uint2*)d)[i] = pk;
}

__global__ void k_bias3(const float* a, const float* b, const float* c, float* dst) {
  int i = blockIdx.x * blockDim.x + threadIdx.x;
  if (i >= 3 * W_DIM) return;
  if (i < W_DIM) dst[i] = a[i];
  else if (i < 2 * W_DIM) dst[i] = b[i - W_DIM];
  else dst[i] = c[i - 2 * W_DIM];
}

__global__ void k_rope_tab(float* __restrict__ tab) {
  int idx = blockIdx.x * blockDim.x + threadIdx.x;
  if (idx >= S_LEN * 512) return;
  int s = idx / 512, i = idx % 512;
  float freq = expf(-(float)i * (9.210340371976184f / 512.0f));
  float ang = (float)s * freq;
  float sv, cv;
  sincosf(ang, &sv, &cv);
  tab[idx * 2 + 0] = cv;
  tab[idx * 2 + 1] = sv;
}

// in-place rotary on cols [0,2048) of qkv1 (row stride 3072 bf16)
__global__ void k_rope(u16* __restrict__ qkv1, const float* __restrict__ tab) {
  int t = blockIdx.x * blockDim.x + threadIdx.x;
  const int total = MROWS * 512 * 2;
  if (t >= total) return;
  int z = t / (MROWS * 512);           // 0=q, 1=k
  int rem = t - z * (MROWS * 512);
  int r = rem >> 9;                    // row (s*256+b)
  int i = rem & 511;                   // pair index
  int s = r >> 8;
  uint32_t* p = (uint32_t*)qkv1 + (size_t)r * 1536 + z * 512 + i;
  uint32_t pv = *p;
  float xe = bf2f((u16)(pv & 0xffffu));
  float xo = bf2f((u16)(pv >> 16));
  float2 cs = ((const float2*)tab)[s * 512 + i];
  float oe = xe * cs.x - xo * cs.y;
  float oo = xe * cs.y + xo * cs.x;
  *p = (uint32_t)f2bf(oe) | ((uint32_t)f2bf(oo) << 16);
}

// ---------------- GEMM: C[M,N] = A[M,K] @ Bw[N,K]^T + bias ----------------
template <int OUT_MODE, int ACOLB>
__global__ __launch_bounds__(256) void k_gemm(
    const u16* __restrict__ A, int lda, const u16* __restrict__ Bw,
    const float* __restrict__ bias, void* __restrict__ Cp, int ldc, int K,
    size_t thirdStride) {
  __shared__ u16 As[128 * 64];
  __shared__ u16 Bs[128 * 64];

  const int tid = threadIdx.x, lane = tid & 63, wave = tid >> 6;
  const int wm = wave >> 1, wn = wave & 1;
  const int m0 = blockIdx.x * 128;
  const int n0 = blockIdx.y * 128;
  const int aoff = ACOLB ? (n0 & ~1023) : 0;

  f32x4 acc[4][4] = {};

  const int lrow = lane >> 3;
  const int lcol = (lane & 7) * 8;
  const u16* Ag = A + (size_t)(m0 + wave * 8 + lrow) * lda + aoff + lcol;
  const u16* Bg = Bw + (size_t)(n0 + wave * 8 + lrow) * K + lcol;
  u16* Asl = As + wave * 8 * 64;
  u16* Bsl = Bs + wave * 8 * 64;

  for (int kt = 0; kt < K; kt += 64) {
#pragma unroll
    for (int i = 0; i < 4; ++i) {
      gload16(Ag + (size_t)(i * 32) * lda + kt, Asl + i * 2048);
      gload16(Bg + (size_t)(i * 32) * K + kt, Bsl + i * 2048);
    }
    __syncthreads();
#pragma unroll
    for (int kk = 0; kk < 2; ++kk) {
      bf16x8 af[4], bfr[4];
#pragma unroll
      for (int m = 0; m < 4; ++m)
        af[m] = *(const bf16x8*)(As + (wm * 64 + m * 16 + (lane & 15)) * 64 + kk * 32 + (lane >> 4) * 8);
#pragma unroll
      for (int n = 0; n < 4; ++n)
        bfr[n] = *(const bf16x8*)(Bs + (wn * 64 + n * 16 + (lane & 15)) * 64 + kk * 32 + (lane >> 4) * 8);
#pragma unroll
      for (int m = 0; m < 4; ++m)
#pragma unroll
        for (int n = 0; n < 4; ++n)
          acc[m][n] = __builtin_amdgcn_mfma_f32_16x16x32_bf16(af[m], bfr[n], acc[m][n], 0, 0, 0);
    }
    __syncthreads();
  }

  const int r0 = (lane >> 4) * 4;
  const int c0 = lane & 15;
#pragma unroll
  for (int m = 0; m < 4; ++m) {
#pragma unroll
    for (int n = 0; n < 4; ++n) {
      const int col = n0 + wn * 64 + n * 16 + c0;
      const float bv = bias[col];
#pragma unroll
      for (int r = 0; r < 4; ++r) {
        const int row = m0 + wm * 64 + m * 16 + r0 + r;
        const float v = acc[m][n][r] + bv;
        if (OUT_MODE == 0) {
          ((u16*)Cp)[(size_t)row * ldc + col] = f2bf(v);
        } else if (OUT_MODE == 2) {
          ((float*)Cp)[(size_t)row * ldc + col] = v;
        } else {
          const int which = col >> 10, c = col & 1023;
          const int h = c >> 6, d = c & 63;
          const int s = row >> 8, b = row & 255;
          ((u16*)Cp)[(size_t)which * thirdStride +
                     (((size_t)(b * NH + h) * S_LEN + s) * HDIM + d)] = f2bf(v);
        }
      }
    }
  }
}

// ---------------- attention: one block per (b,h) ----------------
// Q/K fragments direct from global (L2). V transposed into swizzled LDS.
// Register softmax: shfl_xor over 16-lane col groups + 2-wave LDS combine.
// Pb (P bf16) round-trips through XOR-swizzled LDS for the PV A-operand.
__global__ __launch_bounds__(256) void k_attn(const u16* __restrict__ qkv2,
                                              const float* __restrict__ mask,
                                              u16* __restrict__ O1) {
  __shared__ u16 Vt[64 * 128];     // Vt[d][s ^ ((d&7)<<3)]   16KB
  __shared__ u16 Pb[128 * 128];    // Pb[q][s ^ ((q&7)<<3)]   32KB
  __shared__ float redM[2][128];   // per-wave-column row max
  __shared__ float redS[2][128];   // per-wave-column row sum

  const size_t TS = (size_t)MROWS * W_DIM;
  const int bh = blockIdx.x, b = bh >> 4, h = bh & 15;
  const int tid = threadIdx.x, lane = tid & 63, wave = tid >> 6;
  const int wm = wave >> 1, wn = wave & 1;
  const int c0 = lane & 15, hi = lane >> 4;

  const u16* Qg = qkv2 + (size_t)bh * (S_LEN * HDIM);
  const u16* Kg = Qg + TS;
  const u16* Vg = Qg + 2 * TS;

  // ---- stage V transposed into swizzled Vt (zero-pad s>=97) ----
  for (int idx = tid; idx < 1024; idx += 256) {
    const int s = idx >> 3, c = (idx & 7) * 8;
    uint4 vv = make_uint4(0, 0, 0, 0);
    if (s < S_LEN) vv = *(const uint4*)(Vg + (size_t)s * HDIM + c);
    u16 tmp[8];
    *(uint4*)tmp = vv;
#pragma unroll
    for (int j = 0; j < 8; ++j)
      Vt[(c + j) * 128 + (s ^ (j << 3))] = tmp[j];   // (c+j)&7 == j since c%8==0
  }

  // ---- QK^T, fragments straight from global ----
  f32x4 acc[4][4] = {};
#pragma unroll
  for (int kk = 0; kk < 2; ++kk) {
    bf16x8 af[4], bfr[4];
#pragma unroll
    for (int m = 0; m < 4; ++m)
      af[m] = *(const bf16x8*)(Qg + (size_t)(wm * 64 + m * 16 + c0) * HDIM + kk * 32 + hi * 8);
#pragma unroll
    for (int n = 0; n < 4; ++n)
      bfr[n] = *(const bf16x8*)(Kg + (size_t)(wn * 64 + n * 16 + c0) * HDIM + kk * 32 + hi * 8);
#pragma unroll
    for (int m = 0; m < 4; ++m)
#pragma unroll
      for (int n = 0; n < 4; ++n)
        acc[m][n] = __builtin_amdgcn_mfma_f32_16x16x32_bf16(af[m], bfr[n], acc[m][n], 0, 0, 0);
  }

  // ---- scale + mask + col-pad (-inf), in register ----
#pragma unroll
  for (int m = 0; m < 4; ++m)
#pragma unroll
    for (int n = 0; n < 4; ++n) {
      const int col = wn * 64 + n * 16 + c0;
#pragma unroll
      for (int r = 0; r < 4; ++r) {
        const int row = wm * 64 + m * 16 + hi * 4 + r;
        float v = acc[m][n][r] * 0.125f;
        if (col < S_LEN) {
          if (row < S_LEN) v += mask[row * S_LEN + col];
        } else {
          v = -1e30f;
        }
        acc[m][n][r] = v;
      }
    }

  // ---- row max: register over n, shfl over 16-lane col group ----
  float mx[4][4];
#pragma unroll
  for (int m = 0; m < 4; ++m)
#pragma unroll
    for (int r = 0; r < 4; ++r)
      mx[m][r] = fmaxf(fmaxf(acc[m][0][r], acc[m][1][r]),
                       fmaxf(acc[m][2][r], acc[m][3][r]));
#pragma unroll
  for (int d = 1; d < 16; d <<= 1)
#pragma unroll
    for (int m = 0; m < 4; ++m)
#pragma unroll
      for (int r = 0; r < 4; ++r)
        mx[m][r] = fmaxf(mx[m][r], __shfl_xor(mx[m][r], d));
  if (c0 == 0) {
#pragma unroll
    for (int m = 0; m < 4; ++m)
#pragma unroll
      for (int r = 0; r < 4; ++r)
        redM[wn][wm * 64 + m * 16 + hi * 4 + r] = mx[m][r];
  }
  __syncthreads();   // redM ready; also fences Vt staging

  // ---- exp, partial sums, write P (bf16, swizzled) ----
  float ps[4][4];
#pragma unroll
  for (int m = 0; m < 4; ++m)
#pragma unroll
    for (int r = 0; r < 4; ++r) {
      const int row = wm * 64 + m * 16 + hi * 4 + r;
      const float rm = fmaxf(redM[0][row], redM[1][row]);
      float p = 0.f;
#pragma unroll
      for (int n = 0; n < 4; ++n) {
        const float e = __expf(acc[m][n][r] - rm);
        p += e;
        const int col = wn * 64 + n * 16 + c0;
        Pb[row * 128 + (col ^ ((row & 7) << 3))] = f2bf(e);
      }
      ps[m][r] = p;
    }
#pragma unroll
  for (int d = 1; d < 16; d <<= 1)
#pragma unroll
    for (int m = 0; m < 4; ++m)
#pragma unroll
      for (int r = 0; r < 4; ++r)
        ps[m][r] += __shfl_xor(ps[m][r], d);
  if (c0 == 0) {
#pragma unroll
    for (int m = 0; m < 4; ++m)
#pragma unroll
      for (int r = 0; r < 4; ++r)
        redS[wn][wm * 64 + m * 16 + hi * 4 + r] = ps[m][r];
  }
  __syncthreads();   // Pb + redS ready

  // ---- PV: each wave 64(q) x 32(d) ----
  f32x4 o[4][2] = {};
#pragma unroll
  for (int kk = 0; kk < 4; ++kk) {
    bf16x8 pa[4], vb[2];
#pragma unroll
    for (int m = 0; m < 4; ++m) {
      const int row = wm * 64 + m * 16 + c0;
      pa[m] = *(const bf16x8*)(Pb + row * 128 + ((kk * 32 + hi * 8) ^ ((row & 7) << 3)));
    }
#pragma unroll
    for (int n = 0; n < 2; ++n) {
      const int d = wn * 32 + n * 16 + c0;
      vb[n] = *(const bf16x8*)(Vt + d * 128 + ((kk * 32 + hi * 8) ^ ((d & 7) << 3)));
    }
#pragma unroll
    for (int m = 0; m < 4; ++m)
#pragma unroll
      for (int n = 0; n < 2; ++n)
        o[m][n] = __builtin_amdgcn_mfma_f32_16x16x32_bf16(pa[m], vb[n], o[m][n], 0, 0, 0);
  }

#pragma unroll
  for (int m = 0; m < 4; ++m)
#pragma unroll
    for (int r = 0; r < 4; ++r) {
      const int row = wm * 64 + m * 16 + hi * 4 + r;
      if (row < S_LEN) {
        const float iv = 1.0f / (redS[0][row] + redS[1][row]);
#pragma unroll
        for (int n = 0; n < 2; ++n) {
          const int d = wn * 32 + n * 16 + c0;
          O1[((size_t)row * B_DIM + b) * W_DIM + h * HDIM + d] = f2bf(o[m][n][r] * iv);
        }
      }
    }
}

// ---------------- launcher ----------------
extern "C" void kernel_launch(void* const* d_in, const int* in_sizes, int n_in,
                              void* d_out, int out_size, void* d_ws, size_t ws_size,
                              hipStream_t stream) {
  (void)in_sizes; (void)n_in; (void)out_size; (void)ws_size;
  const float* tensor    = (const float*)d_in[0];
  const float* mask      = (const float*)d_in[1];
  const float* q_w       = (const float*)d_in[2];
  const float* q_b       = (const float*)d_in[3];
  const float* k_w       = (const float*)d_in[4];
  const float* k_b       = (const float*)d_in[5];
  const float* v_w       = (const float*)d_in[6];
  const float* v_b       = (const float*)d_in[7];
  const float* in_proj_w = (const float*)d_in[8];
  const float* in_proj_b = (const float*)d_in[9];
  const float* mha_w     = (const float*)d_in[10];
  const float* mha_b     = (const float*)d_in[11];
  const float* out_w     = (const float*)d_in[12];
  const float* out_b     = (const float*)d_in[13];

  char* ws = (char*)d_ws;
  size_t off = 0;
  auto alloc = [&](size_t bytes) {
    char* p = ws + off;
    off += (bytes + 255) & ~(size_t)255;
    return p;
  };

  float* tab = (float*)alloc((size_t)S_LEN * 512 * 2 * sizeof(float));
  u16* Xbf   = (u16*)alloc((size_t)MROWS * W_DIM * 2);       // reused as O1
  u16* qkv1  = (u16*)alloc((size_t)MROWS * 3 * W_DIM * 2);   // head reused as O2
  u16* qkv2  = (u16*)alloc((size_t)MROWS * 3 * W_DIM * 2);
  u16* WC1   = (u16*)alloc((size_t)3 * W_DIM * W_DIM * 2);
  u16* W2    = (u16*)alloc((size_t)3 * W_DIM * W_DIM * 2);
  u16* WM    = (u16*)alloc((size_t)W_DIM * W_DIM * 2);
  u16* WO    = (u16*)alloc((size_t)W_DIM * W_DIM * 2);
  float* bc1 = (float*)alloc(3 * W_DIM * sizeof(float));
  u16* O1 = Xbf;   // X dead after GEMM1
  u16* O2 = qkv1;  // qkv1 dead after GEMM2

  // prep
  k_rope_tab<<<dim3((S_LEN * 512 + 255) / 256), 256, 0, stream>>>(tab);
  k_cvt<<<dim3(MROWS * W_DIM / 4 / 256), 256, 0, stream>>>(tensor, Xbf, MROWS * W_DIM / 4);
  k_cvt<<<dim3(1024), 256, 0, stream>>>(q_w, WC1, 262144);
  k_cvt<<<dim3(1024), 256, 0, stream>>>(k_w, WC1 + 1048576, 262144);
  k_cvt<<<dim3(1024), 256, 0, stream>>>(v_w, WC1 + 2097152, 262144);
  k_cvt<<<dim3(3072), 256, 0, stream>>>(in_proj_w, W2, 786432);
  k_cvt<<<dim3(1024), 256, 0, stream>>>(mha_w, WM, 262144);
  k_cvt<<<dim3(1024), 256, 0, stream>>>(out_w, WO, 262144);
  k_bias3<<<dim3(12), 256, 0, stream>>>(q_b, k_b, v_b, bc1);

  // GEMM1: X @ [q_w;k_w;v_w]^T + bias -> qkv1 (24832 x 3072)
  k_gemm<0, 0><<<dim3(MROWS / 128, 3072 / 128), 256, 0, stream>>>(
      Xbf, W_DIM, WC1, bc1, qkv1, 3072, W_DIM, 0);

  // rotary in place on q,k columns
  k_rope<<<dim3(MROWS * 512 * 2 / 256), 256, 0, stream>>>(qkv1, tab);

  // GEMM2 (block-diagonal): qkv1 @ in_proj^T + in_proj_b -> qkv2 in (B,H,S,HD)
  k_gemm<1, 1><<<dim3(MROWS / 128, 3072 / 128), 256, 0, stream>>>(
      qkv1, 3072, W2, in_proj_b, qkv2, 0, W_DIM, (size_t)MROWS * W_DIM);

  // attention
  k_attn<<<dim3(B_DIM * NH), 256, 0, stream>>>(qkv2, mask, O1);

  // output projections
  k_gemm<0, 0><<<dim3(MROWS / 128, W_DIM / 128), 256, 0, stream>>>(
      O1, W_DIM, WM, mha_b, O2, W_DIM, W_DIM, 0);
  k_gemm<2, 0><<<dim3(MROWS / 128, W_DIM / 128), 256, 0, stream>>>(
      O2, W_DIM, WO, out_b, d_out, W_DIM, W_DIM, 0);
}

// Round 3
// 856.300 us; speedup vs baseline: 1.2842x; 1.1691x over previous
//
#include <hip/hip_runtime.h>
#include <cstdint>
#include <cstddef>

#define S_LEN 97
#define B_DIM 256
#define W_DIM 1024
#define NH    16
#define HDIM  64
#define MROWS (S_LEN * B_DIM)   // 24832 = 194*128

typedef unsigned short u16;
typedef __bf16 bf16x8 __attribute__((ext_vector_type(8)));
typedef float  f32x4  __attribute__((ext_vector_type(4)));

__device__ __forceinline__ u16 f2bf(float f) {
  union { float f; uint32_t u; } v; v.f = f;
  uint32_t u = v.u;
  return (u16)((u + 0x7FFFu + ((u >> 16) & 1u)) >> 16);  // RNE
}
__device__ __forceinline__ float bf2f(u16 h) {
  union { uint32_t u; float f; } v; v.u = ((uint32_t)h) << 16;
  return v.f;
}

// async global->LDS, 16B per lane. LDS dest must be wave-uniform base; HW adds lane*16.
__device__ __forceinline__ void gload16(const void* g, void* lds) {
  __builtin_amdgcn_global_load_lds(
      (const __attribute__((address_space(1))) void*)(uintptr_t)g,
      (__attribute__((address_space(3))) void*)(uint32_t)(uintptr_t)lds,
      16, 0, 0);
}

// ---------------- prep kernels ----------------
__global__ void k_cvt(const float* __restrict__ s, u16* __restrict__ d, int n4) {
  int i = blockIdx.x * blockDim.x + threadIdx.x;
  if (i >= n4) return;
  float4 v = ((const float4*)s)[i];
  uint2 pk;
  pk.x = (uint32_t)f2bf(v.x) | ((uint32_t)f2bf(v.y) << 16);
  pk.y = (uint32_t)f2bf(v.z) | ((uint32_t)f2bf(v.w) << 16);
  ((uint2*)d)[i] = pk;
}

// dst = src^T (1024x1024), fp32 -> bf16
__global__ void k_cvt_t(const float* __restrict__ src, u16* __restrict__ dst) {
  __shared__ float t[32][33];
  const int bx = blockIdx.x * 32, by = blockIdx.y * 32;
  const int tx = threadIdx.x, ty = threadIdx.y;  // 32 x 8
  for (int yy = ty; yy < 32; yy += 8)
    t[yy][tx] = src[(size_t)(by + yy) * 1024 + bx + tx];
  __syncthreads();
  for (int yy = ty; yy < 32; yy += 8)
    dst[(size_t)(bx + yy) * 1024 + by + tx] = f2bf(t[tx][yy]);
}

__global__ void k_bias2(const float* a, const float* b, float* dst) {
  int i = blockIdx.x * blockDim.x + threadIdx.x;
  if (i >= 2 * W_DIM) return;
  dst[i] = (i < W_DIM) ? a[i] : b[i - W_DIM];
}

__global__ void k_zero(float* dst, int n) {
  int i = blockIdx.x * blockDim.x + threadIdx.x;
  if (i < n) dst[i] = 0.f;
}

// out[row] = dot(M[row,:], v) + b2[row]   (M: 1024x1024 fp32)
__global__ void k_biasfold(const float* __restrict__ M, const float* __restrict__ v,
                           const float* __restrict__ b2, float* __restrict__ out) {
  const int lane = threadIdx.x & 63, wave = threadIdx.x >> 6;
  const int row = blockIdx.x * 4 + wave;
  float s = 0.f;
  for (int k = lane; k < 1024; k += 64) s += M[(size_t)row * 1024 + k] * v[k];
#pragma unroll
  for (int d = 32; d; d >>= 1) s += __shfl_xor(s, d);
  if (lane == 0) out[row] = s + b2[row];
}

__global__ void k_rope_tab(float* __restrict__ tab) {
  int idx = blockIdx.x * blockDim.x + threadIdx.x;
  if (idx >= S_LEN * 512) return;
  int s = idx / 512, i = idx % 512;
  float freq = expf(-(float)i * (9.210340371976184f / 512.0f));
  float ang = (float)s * freq;
  float sv, cv;
  sincosf(ang, &sv, &cv);
  tab[idx * 2 + 0] = cv;
  tab[idx * 2 + 1] = sv;
}

// ---------------- GEMM: C[M,N] = A[M,K] @ Bw[N,K]^T + bias ----------------
// OUT_MODE: 0 = bf16 row-major, 1 = qkv-head layout bf16, 2 = f32 row-major,
//           3 = bf16 row-major + fused rotary (q cols [0,1024), k cols [1024,2048))
// ACOLB: A column offset = (n0 & ~1023)  (block-diagonal projection)
// grid: x = n-tiles, y = m-tiles (consecutive blocks share the A panel -> L2)
template <int OUT_MODE, int ACOLB>
__global__ __launch_bounds__(256) void k_gemm(
    const u16* __restrict__ A, int lda, const u16* __restrict__ Bw,
    const float* __restrict__ bias, void* __restrict__ Cp, int ldc, int K,
    size_t thirdStride, const float* __restrict__ tab) {
  __shared__ u16 As[128 * 64];
  __shared__ u16 Bs[128 * 64];

  const int tid = threadIdx.x, lane = tid & 63, wave = tid >> 6;
  const int wm = wave >> 1, wn = wave & 1;
  const int m0 = blockIdx.y * 128;
  const int n0 = blockIdx.x * 128;
  const int aoff = ACOLB ? (n0 & ~1023) : 0;

  f32x4 acc[4][4] = {};

  const int lrow = lane >> 3;
  const int lcol = (lane & 7) * 8;
  const u16* Ag = A + (size_t)(m0 + wave * 8 + lrow) * lda + aoff + lcol;
  const u16* Bg = Bw + (size_t)(n0 + wave * 8 + lrow) * K + lcol;
  u16* Asl = As + wave * 8 * 64;
  u16* Bsl = Bs + wave * 8 * 64;

  for (int kt = 0; kt < K; kt += 64) {
#pragma unroll
    for (int i = 0; i < 4; ++i) {
      gload16(Ag + (size_t)(i * 32) * lda + kt, Asl + i * 2048);
      gload16(Bg + (size_t)(i * 32) * K + kt, Bsl + i * 2048);
    }
    __syncthreads();
#pragma unroll
    for (int kk = 0; kk < 2; ++kk) {
      bf16x8 af[4], bfr[4];
#pragma unroll
      for (int m = 0; m < 4; ++m)
        af[m] = *(const bf16x8*)(As + (wm * 64 + m * 16 + (lane & 15)) * 64 + kk * 32 + (lane >> 4) * 8);
#pragma unroll
      for (int n = 0; n < 4; ++n)
        bfr[n] = *(const bf16x8*)(Bs + (wn * 64 + n * 16 + (lane & 15)) * 64 + kk * 32 + (lane >> 4) * 8);
#pragma unroll
      for (int m = 0; m < 4; ++m)
#pragma unroll
        for (int n = 0; n < 4; ++n)
          acc[m][n] = __builtin_amdgcn_mfma_f32_16x16x32_bf16(af[m], bfr[n], acc[m][n], 0, 0, 0);
    }
    __syncthreads();
  }

  const int r0 = (lane >> 4) * 4;
  const int c0 = lane & 15;
#pragma unroll
  for (int m = 0; m < 4; ++m) {
#pragma unroll
    for (int n = 0; n < 4; ++n) {
      const int col = n0 + wn * 64 + n * 16 + c0;
      const float bv = bias[col];
      if (OUT_MODE == 3) {
        // fused rotary: pair (2i,2i+1) lives in adjacent lanes (c0 parity)
        const int pairI = (col & 1023) >> 1;
        const float sgn = (col & 1) ? 1.f : -1.f;
#pragma unroll
        for (int r = 0; r < 4; ++r) {
          const int row = m0 + wm * 64 + m * 16 + r0 + r;
          const float v = acc[m][n][r] + bv;
          const float p = __shfl_xor(v, 1);
          const float2 cs = ((const float2*)tab)[(row >> 8) * 512 + pairI];
          ((u16*)Cp)[(size_t)row * ldc + col] = f2bf(v * cs.x + sgn * p * cs.y);
        }
      } else {
#pragma unroll
        for (int r = 0; r < 4; ++r) {
          const int row = m0 + wm * 64 + m * 16 + r0 + r;
          const float v = acc[m][n][r] + bv;
          if (OUT_MODE == 0) {
            ((u16*)Cp)[(size_t)row * ldc + col] = f2bf(v);
          } else if (OUT_MODE == 2) {
            ((float*)Cp)[(size_t)row * ldc + col] = v;
          } else {
            const int which = col >> 10, c = col & 1023;
            const int h = c >> 6, d = c & 63;
            const int s = row >> 8, b = row & 255;
            ((u16*)Cp)[(size_t)which * thirdStride +
                       (((size_t)(b * NH + h) * S_LEN + s) * HDIM + d)] = f2bf(v);
          }
        }
      }
    }
  }
}

// ---------------- attention: one block per (b,h) ----------------
__global__ __launch_bounds__(256) void k_attn(const u16* __restrict__ qkv2,
                                              const float* __restrict__ mask,
                                              u16* __restrict__ O1) {
  __shared__ u16 Vt[64 * 128];     // Vt[d][s ^ ((d&7)<<3)]   16KB
  __shared__ u16 Pb[128 * 128];    // Pb[q][s ^ ((q&7)<<3)]   32KB
  __shared__ float redM[2][128];
  __shared__ float redS[2][128];

  const size_t TS = (size_t)MROWS * W_DIM;
  const int bh = blockIdx.x, b = bh >> 4, h = bh & 15;
  const int tid = threadIdx.x, lane = tid & 63, wave = tid >> 6;
  const int wm = wave >> 1, wn = wave & 1;
  const int c0 = lane & 15, hi = lane >> 4;

  const u16* Qg = qkv2 + (size_t)bh * (S_LEN * HDIM);
  const u16* Kg = Qg + TS;
  const u16* Vg = Qg + 2 * TS;

  for (int idx = tid; idx < 1024; idx += 256) {
    const int s = idx >> 3, c = (idx & 7) * 8;
    uint4 vv = make_uint4(0, 0, 0, 0);
    if (s < S_LEN) vv = *(const uint4*)(Vg + (size_t)s * HDIM + c);
    u16 tmp[8];
    *(uint4*)tmp = vv;
#pragma unroll
    for (int j = 0; j < 8; ++j)
      Vt[(c + j) * 128 + (s ^ (j << 3))] = tmp[j];
  }

  f32x4 acc[4][4] = {};
#pragma unroll
  for (int kk = 0; kk < 2; ++kk) {
    bf16x8 af[4], bfr[4];
#pragma unroll
    for (int m = 0; m < 4; ++m)
      af[m] = *(const bf16x8*)(Qg + (size_t)(wm * 64 + m * 16 + c0) * HDIM + kk * 32 + hi * 8);
#pragma unroll
    for (int n = 0; n < 4; ++n)
      bfr[n] = *(const bf16x8*)(Kg + (size_t)(wn * 64 + n * 16 + c0) * HDIM + kk * 32 + hi * 8);
#pragma unroll
    for (int m = 0; m < 4; ++m)
#pragma unroll
      for (int n = 0; n < 4; ++n)
        acc[m][n] = __builtin_amdgcn_mfma_f32_16x16x32_bf16(af[m], bfr[n], acc[m][n], 0, 0, 0);
  }

#pragma unroll
  for (int m = 0; m < 4; ++m)
#pragma unroll
    for (int n = 0; n < 4; ++n) {
      const int col = wn * 64 + n * 16 + c0;
#pragma unroll
      for (int r = 0; r < 4; ++r) {
        const int row = wm * 64 + m * 16 + hi * 4 + r;
        float v = acc[m][n][r] * 0.125f;
        if (col < S_LEN) {
          if (row < S_LEN) v += mask[row * S_LEN + col];
        } else {
          v = -1e30f;
        }
        acc[m][n][r] = v;
      }
    }

  float mx[4][4];
#pragma unroll
  for (int m = 0; m < 4; ++m)
#pragma unroll
    for (int r = 0; r < 4; ++r)
      mx[m][r] = fmaxf(fmaxf(acc[m][0][r], acc[m][1][r]),
                       fmaxf(acc[m][2][r], acc[m][3][r]));
#pragma unroll
  for (int d = 1; d < 16; d <<= 1)
#pragma unroll
    for (int m = 0; m < 4; ++m)
#pragma unroll
      for (int r = 0; r < 4; ++r)
        mx[m][r] = fmaxf(mx[m][r], __shfl_xor(mx[m][r], d));
  if (c0 == 0) {
#pragma unroll
    for (int m = 0; m < 4; ++m)
#pragma unroll
      for (int r = 0; r < 4; ++r)
        redM[wn][wm * 64 + m * 16 + hi * 4 + r] = mx[m][r];
  }
  __syncthreads();

  float ps[4][4];
#pragma unroll
  for (int m = 0; m < 4; ++m)
#pragma unroll
    for (int r = 0; r < 4; ++r) {
      const int row = wm * 64 + m * 16 + hi * 4 + r;
      const float rm = fmaxf(redM[0][row], redM[1][row]);
      float p = 0.f;
#pragma unroll
      for (int n = 0; n < 4; ++n) {
        const float e = __expf(acc[m][n][r] - rm);
        p += e;
        const int col = wn * 64 + n * 16 + c0;
        Pb[row * 128 + (col ^ ((row & 7) << 3))] = f2bf(e);
      }
      ps[m][r] = p;
    }
#pragma unroll
  for (int d = 1; d < 16; d <<= 1)
#pragma unroll
    for (int m = 0; m < 4; ++m)
#pragma unroll
      for (int r = 0; r < 4; ++r)
        ps[m][r] += __shfl_xor(ps[m][r], d);
  if (c0 == 0) {
#pragma unroll
    for (int m = 0; m < 4; ++m)
#pragma unroll
      for (int r = 0; r < 4; ++r)
        redS[wn][wm * 64 + m * 16 + hi * 4 + r] = ps[m][r];
  }
  __syncthreads();

  f32x4 o[4][2] = {};
#pragma unroll
  for (int kk = 0; kk < 4; ++kk) {
    bf16x8 pa[4], vb[2];
#pragma unroll
    for (int m = 0; m < 4; ++m) {
      const int row = wm * 64 + m * 16 + c0;
      pa[m] = *(const bf16x8*)(Pb + row * 128 + ((kk * 32 + hi * 8) ^ ((row & 7) << 3)));
    }
#pragma unroll
    for (int n = 0; n < 2; ++n) {
      const int d = wn * 32 + n * 16 + c0;
      vb[n] = *(const bf16x8*)(Vt + d * 128 + ((kk * 32 + hi * 8) ^ ((d & 7) << 3)));
    }
#pragma unroll
    for (int m = 0; m < 4; ++m)
#pragma unroll
      for (int n = 0; n < 2; ++n)
        o[m][n] = __builtin_amdgcn_mfma_f32_16x16x32_bf16(pa[m], vb[n], o[m][n], 0, 0, 0);
  }

#pragma unroll
  for (int m = 0; m < 4; ++m)
#pragma unroll
    for (int r = 0; r < 4; ++r) {
      const int row = wm * 64 + m * 16 + hi * 4 + r;
      if (row < S_LEN) {
        const float iv = 1.0f / (redS[0][row] + redS[1][row]);
#pragma unroll
        for (int n = 0; n < 2; ++n) {
          const int d = wn * 32 + n * 16 + c0;
          O1[((size_t)row * B_DIM + b) * W_DIM + h * HDIM + d] = f2bf(o[m][n][r] * iv);
        }
      }
    }
}

// ---------------- launcher ----------------
extern "C" void kernel_launch(void* const* d_in, const int* in_sizes, int n_in,
                              void* d_out, int out_size, void* d_ws, size_t ws_size,
                              hipStream_t stream) {
  (void)in_sizes; (void)n_in; (void)out_size; (void)ws_size;
  const float* tensor    = (const float*)d_in[0];
  const float* mask      = (const float*)d_in[1];
  const float* q_w       = (const float*)d_in[2];
  const float* q_b       = (const float*)d_in[3];
  const float* k_w       = (const float*)d_in[4];
  const float* k_b       = (const float*)d_in[5];
  const float* v_w       = (const float*)d_in[6];
  const float* v_b       = (const float*)d_in[7];
  const float* in_proj_w = (const float*)d_in[8];
  const float* in_proj_b = (const float*)d_in[9];
  const float* mha_w     = (const float*)d_in[10];
  const float* mha_b     = (const float*)d_in[11];
  const float* out_w     = (const float*)d_in[12];
  const float* out_b     = (const float*)d_in[13];

  char* ws = (char*)d_ws;
  size_t off = 0;
  auto alloc = [&](size_t bytes) {
    char* p = ws + off;
    off += (bytes + 255) & ~(size_t)255;
    return p;
  };

  const size_t TS = (size_t)MROWS * W_DIM;

  float* tab = (float*)alloc((size_t)S_LEN * 512 * 2 * sizeof(float));
  u16* Xbf   = (u16*)alloc(TS * 2);                          // reused as O1
  u16* qkv1  = (u16*)alloc((size_t)MROWS * 2048 * 2);        // q,k after GEMM1+rope
  u16* qkv2  = (u16*)alloc(TS * 3 * 2);                      // q,k,v head layout
  u16* WC1   = (u16*)alloc((size_t)2048 * 1024 * 2);         // [q_w;k_w] bf16
  u16* W2    = (u16*)alloc((size_t)3072 * 1024 * 2);         // in_proj bf16
  u16* WvT   = (u16*)alloc((size_t)1024 * 1024 * 2);
  u16* WmT   = (u16*)alloc((size_t)1024 * 1024 * 2);
  u16* WO    = (u16*)alloc((size_t)1024 * 1024 * 2);
  u16* WVf   = (u16*)alloc((size_t)1024 * 1024 * 2);         // Wv2 @ Wv
  u16* WFf   = (u16*)alloc((size_t)1024 * 1024 * 2);         // Wo @ Wm
  float* bc1 = (float*)alloc(2048 * sizeof(float));
  float* bvf = (float*)alloc(1024 * sizeof(float));
  float* bff = (float*)alloc(1024 * sizeof(float));
  float* zb  = (float*)alloc(1024 * sizeof(float));
  u16* O1 = Xbf;  // X dead after GEMM_v

  // ---- prep / converts ----
  k_rope_tab<<<dim3((S_LEN * 512 + 255) / 256), 256, 0, stream>>>(tab);
  k_cvt<<<dim3(MROWS * W_DIM / 4 / 256), 256, 0, stream>>>(tensor, Xbf, MROWS * W_DIM / 4);
  k_cvt<<<dim3(1024), 256, 0, stream>>>(q_w, WC1, 262144);
  k_cvt<<<dim3(1024), 256, 0, stream>>>(k_w, WC1 + 1048576, 262144);
  k_cvt<<<dim3(3072), 256, 0, stream>>>(in_proj_w, W2, 786432);
  k_cvt<<<dim3(1024), 256, 0, stream>>>(out_w, WO, 262144);
  k_cvt_t<<<dim3(32, 32), dim3(32, 8), 0, stream>>>(v_w, WvT);
  k_cvt_t<<<dim3(32, 32), dim3(32, 8), 0, stream>>>(mha_w, WmT);
  k_bias2<<<dim3(8), 256, 0, stream>>>(q_b, k_b, bc1);
  k_zero<<<dim3(4), 256, 0, stream>>>(zb, 1024);
  k_biasfold<<<dim3(256), 256, 0, stream>>>(in_proj_w + (size_t)2048 * 1024, v_b,
                                            in_proj_b + 2048, bvf);
  k_biasfold<<<dim3(256), 256, 0, stream>>>(out_w, mha_b, out_b, bff);

  // ---- weight folds (1024^3 bf16 GEMMs) ----
  // WVf = Wv2 @ Wv ;  WFf = Wo @ Wm
  k_gemm<0, 0><<<dim3(8, 8), 256, 0, stream>>>(
      W2 + (size_t)2048 * 1024, 1024, WvT, zb, WVf, 1024, 1024, 0, nullptr);
  k_gemm<0, 0><<<dim3(8, 8), 256, 0, stream>>>(
      WO, 1024, WmT, zb, WFf, 1024, 1024, 0, nullptr);

  // ---- GEMM1 + fused rope: X @ [q_w;k_w]^T + bias -> qkv1 (24832 x 2048) ----
  k_gemm<3, 0><<<dim3(16, MROWS / 128), 256, 0, stream>>>(
      Xbf, W_DIM, WC1, bc1, qkv1, 2048, W_DIM, 0, tab);

  // ---- v path (folded): X @ WVf^T + bvf -> v heads ----
  k_gemm<1, 0><<<dim3(8, MROWS / 128), 256, 0, stream>>>(
      Xbf, W_DIM, WVf, bvf, qkv2 + 2 * TS, 0, W_DIM, TS, nullptr);

  // ---- GEMM2 (block-diagonal): qkv1 @ [Wq2;Wk2]^T + b -> q,k heads ----
  k_gemm<1, 1><<<dim3(16, MROWS / 128), 256, 0, stream>>>(
      qkv1, 2048, W2, in_proj_b, qkv2, 0, W_DIM, TS, nullptr);

  // ---- attention ----
  k_attn<<<dim3(B_DIM * NH), 256, 0, stream>>>(qkv2, mask, O1);

  // ---- output (folded): O1 @ WFf^T + bff -> d_out (fp32) ----
  k_gemm<2, 0><<<dim3(8, MROWS / 128), 256, 0, stream>>>(
      O1, W_DIM, WFf, bff, d_out, W_DIM, W_DIM, 0, nullptr);
}

// Round 4
// 715.802 us; speedup vs baseline: 1.5362x; 1.1963x over previous
//
#include <hip/hip_runtime.h>
#include <cstdint>
#include <cstddef>

#define S_LEN 97
#define B_DIM 256
#define W_DIM 1024
#define NH    16
#define HDIM  64
#define MROWS (S_LEN * B_DIM)   // 24832 = 97*256

typedef unsigned short u16;
typedef __bf16 bf16x8 __attribute__((ext_vector_type(8)));
typedef float  f32x4  __attribute__((ext_vector_type(4)));

__device__ __forceinline__ u16 f2bf(float f) {
  union { float f; uint32_t u; } v; v.f = f;
  uint32_t u = v.u;
  return (u16)((u + 0x7FFFu + ((u >> 16) & 1u)) >> 16);  // RNE
}
__device__ __forceinline__ float bf2f(u16 h) {
  union { uint32_t u; float f; } v; v.u = ((uint32_t)h) << 16;
  return v.f;
}

// async global->LDS, 16B per lane. LDS dest must be wave-uniform base; HW adds lane*16.
__device__ __forceinline__ void gload16(const void* g, void* lds) {
  __builtin_amdgcn_global_load_lds(
      (const __attribute__((address_space(1))) void*)(uintptr_t)g,
      (__attribute__((address_space(3))) void*)(uint32_t)(uintptr_t)lds,
      16, 0, 0);
}

// ---------------- prep kernels ----------------
__global__ void k_cvt(const float* __restrict__ s, u16* __restrict__ d, int n4) {
  int i = blockIdx.x * blockDim.x + threadIdx.x;
  if (i >= n4) return;
  float4 v = ((const float4*)s)[i];
  uint2 pk;
  pk.x = (uint32_t)f2bf(v.x) | ((uint32_t)f2bf(v.y) << 16);
  pk.y = (uint32_t)f2bf(v.z) | ((uint32_t)f2bf(v.w) << 16);
  ((uint2*)d)[i] = pk;
}

// dst = src^T (1024x1024), fp32 -> bf16
__global__ void k_cvt_t(const float* __restrict__ src, u16* __restrict__ dst) {
  __shared__ float t[32][33];
  const int bx = blockIdx.x * 32, by = blockIdx.y * 32;
  const int tx = threadIdx.x, ty = threadIdx.y;  // 32 x 8
  for (int yy = ty; yy < 32; yy += 8)
    t[yy][tx] = src[(size_t)(by + yy) * 1024 + bx + tx];
  __syncthreads();
  for (int yy = ty; yy < 32; yy += 8)
    dst[(size_t)(bx + yy) * 1024 + by + tx] = f2bf(t[tx][yy]);
}

__global__ void k_bias2(const float* a, const float* b, float* dst) {
  int i = blockIdx.x * blockDim.x + threadIdx.x;
  if (i >= 2 * W_DIM) return;
  dst[i] = (i < W_DIM) ? a[i] : b[i - W_DIM];
}

__global__ void k_zero(float* dst, int n) {
  int i = blockIdx.x * blockDim.x + threadIdx.x;
  if (i < n) dst[i] = 0.f;
}

// out[row] = dot(M[row,:], v) + b2[row]   (M: 1024x1024 fp32)
__global__ void k_biasfold(const float* __restrict__ M, const float* __restrict__ v,
                           const float* __restrict__ b2, float* __restrict__ out) {
  const int lane = threadIdx.x & 63, wave = threadIdx.x >> 6;
  const int row = blockIdx.x * 4 + wave;
  float s = 0.f;
  for (int k = lane; k < 1024; k += 64) s += M[(size_t)row * 1024 + k] * v[k];
#pragma unroll
  for (int d = 32; d; d >>= 1) s += __shfl_xor(s, d);
  if (lane == 0) out[row] = s + b2[row];
}

__global__ void k_rope_tab(float* __restrict__ tab) {
  int idx = blockIdx.x * blockDim.x + threadIdx.x;
  if (idx >= S_LEN * 512) return;
  int s = idx / 512, i = idx % 512;
  float freq = expf(-(float)i * (9.210340371976184f / 512.0f));
  float ang = (float)s * freq;
  float sv, cv;
  sincosf(ang, &sv, &cv);
  tab[idx * 2 + 0] = cv;
  tab[idx * 2 + 1] = sv;
}

// ---------------- small 128x128 GEMM (weight folds only) ----------------
template <int OUT_MODE, int ACOLB>
__global__ __launch_bounds__(256) void k_gemm(
    const u16* __restrict__ A, int lda, const u16* __restrict__ Bw,
    const float* __restrict__ bias, void* __restrict__ Cp, int ldc, int K,
    size_t thirdStride, const float* __restrict__ tab) {
  __shared__ u16 As[128 * 64];
  __shared__ u16 Bs[128 * 64];

  const int tid = threadIdx.x, lane = tid & 63, wave = tid >> 6;
  const int wm = wave >> 1, wn = wave & 1;
  const int m0 = blockIdx.y * 128;
  const int n0 = blockIdx.x * 128;
  const int aoff = ACOLB ? (n0 & ~1023) : 0;

  f32x4 acc[4][4] = {};

  const int lrow = lane >> 3;
  const int lcol = (lane & 7) * 8;
  const u16* Ag = A + (size_t)(m0 + wave * 8 + lrow) * lda + aoff + lcol;
  const u16* Bg = Bw + (size_t)(n0 + wave * 8 + lrow) * K + lcol;
  u16* Asl = As + wave * 8 * 64;
  u16* Bsl = Bs + wave * 8 * 64;

  for (int kt = 0; kt < K; kt += 64) {
#pragma unroll
    for (int i = 0; i < 4; ++i) {
      gload16(Ag + (size_t)(i * 32) * lda + kt, Asl + i * 2048);
      gload16(Bg + (size_t)(i * 32) * K + kt, Bsl + i * 2048);
    }
    __syncthreads();
#pragma unroll
    for (int kk = 0; kk < 2; ++kk) {
      bf16x8 af[4], bfr[4];
#pragma unroll
      for (int m = 0; m < 4; ++m)
        af[m] = *(const bf16x8*)(As + (wm * 64 + m * 16 + (lane & 15)) * 64 + kk * 32 + (lane >> 4) * 8);
#pragma unroll
      for (int n = 0; n < 4; ++n)
        bfr[n] = *(const bf16x8*)(Bs + (wn * 64 + n * 16 + (lane & 15)) * 64 + kk * 32 + (lane >> 4) * 8);
#pragma unroll
      for (int m = 0; m < 4; ++m)
#pragma unroll
        for (int n = 0; n < 4; ++n)
          acc[m][n] = __builtin_amdgcn_mfma_f32_16x16x32_bf16(af[m], bfr[n], acc[m][n], 0, 0, 0);
    }
    __syncthreads();
  }

  const int r0 = (lane >> 4) * 4;
  const int c0 = lane & 15;
#pragma unroll
  for (int m = 0; m < 4; ++m) {
#pragma unroll
    for (int n = 0; n < 4; ++n) {
      const int col = n0 + wn * 64 + n * 16 + c0;
      const float bv = bias[col];
#pragma unroll
      for (int r = 0; r < 4; ++r) {
        const int row = m0 + wm * 64 + m * 16 + r0 + r;
        const float v = acc[m][n][r] + bv;
        if (OUT_MODE == 0) {
          ((u16*)Cp)[(size_t)row * ldc + col] = f2bf(v);
        } else if (OUT_MODE == 2) {
          ((float*)Cp)[(size_t)row * ldc + col] = v;
        }
      }
    }
  }
  (void)thirdStride; (void)tab;
}

// ---------------- 256x256 pipelined GEMM (K=1024 fixed) ----------------
// C[M,N] = A[M,K=1024] @ Bw[N,1024]^T + bias
// 8 waves (2M x 4N), per-wave 128x64. BK=32, 32 K-tiles.
// 3 LDS buffers, depth-2 prefetch, counted vmcnt(4) at tile boundaries (T3/T4).
// Chunk-XOR LDS swizzle via pre-swizzled global source (T2). setprio around MFMA (T5).
// Bijective XCD grid swizzle, n-inner (T1).
// OUT_MODE: 0 bf16 row-major, 1 qkv-head scatter, 2 f32 row-major, 3 bf16+rope
template <int OUT_MODE, int ACOLB>
__global__ __launch_bounds__(512, 2) void k_gemm256(
    const u16* __restrict__ A, int lda, const u16* __restrict__ Bw,
    const float* __restrict__ bias, void* __restrict__ Cp, int ldc,
    size_t thirdStride, const float* __restrict__ tab, int Nt) {
  __shared__ u16 lds[3 * 16384];  // 3 x (A 16KB + B 16KB) = 96KB

  const int tid = threadIdx.x, lane = tid & 63, wave = tid >> 6;
  const int wm = wave >> 2, wn = wave & 3;

  // bijective XCD swizzle (m204), n-tile inner
  const int nwg = gridDim.x;
  const int qq = nwg >> 3, rr_ = nwg & 7;
  const int xcd = blockIdx.x & 7, sub = blockIdx.x >> 3;
  const int seq = (xcd < rr_ ? xcd * (qq + 1) : rr_ * (qq + 1) + (xcd - rr_) * qq) + sub;
  const int mt = seq / Nt, nt = seq - mt * Nt;
  const int m0 = mt * 256, n0 = nt * 256;
  const int aoff = ACOLB ? (n0 & ~1023) : 0;

  // staging geometry: one wave-load = 16 rows x 32 k (1KB). 2 rounds each for A,B.
  // lane l: row_in = l>>2, phys chunk = l&3, logical chunk = (l&3)^(row&3)  [T2 inverse-swz source]
  const int srow = lane >> 2;
  const int lch = (lane & 3) ^ (srow & 3);
  const u16* agb[2]; const u16* bgb[2];
  uint32_t aldsb[2], bldsb[2];
#pragma unroll
  for (int rr = 0; rr < 2; ++rr) {
    const int row = (rr * 8 + wave) * 16 + srow;
    agb[rr] = A + (size_t)(m0 + row) * lda + aoff + lch * 8;
    bgb[rr] = Bw + (size_t)(n0 + row) * 1024 + lch * 8;
    aldsb[rr] = (uint32_t)((rr * 8 + wave) * 1024);           // byte off in A half
    bldsb[rr] = (uint32_t)(16384 + (rr * 8 + wave) * 1024);   // byte off in B half
  }

  auto stage = [&](int t, int rr, int cbytes) {
    gload16(agb[rr] + t * 32, (char*)lds + cbytes + aldsb[rr]);
    gload16(bgb[rr] + t * 32, (char*)lds + cbytes + bldsb[rr]);
  };

  // read offsets (u16 units within buffer); row&3 == lane&3 for all frags
  const int chunkoff = ((lane >> 4) ^ (lane & 3)) * 8;
  int aofr[8], bofr[4];
#pragma unroll
  for (int m = 0; m < 8; ++m)
    aofr[m] = (wm * 128 + m * 16 + (lane & 15)) * 32 + chunkoff;
#pragma unroll
  for (int n = 0; n < 4; ++n)
    bofr[n] = 8192 + (wn * 64 + n * 16 + (lane & 15)) * 32 + chunkoff;

  // prologue: stage tiles 0,1 -> wait tile 0 only (counted)
#pragma unroll
  for (int t = 0; t < 2; ++t) {
    stage(t, 0, t * 32768);
    stage(t, 1, t * 32768);
  }
  asm volatile("s_waitcnt vmcnt(4)" ::: "memory");
  __builtin_amdgcn_s_barrier();

  f32x4 acc[8][4] = {};
  int cur = 0;
  for (int t = 0; t < 32; ++t) {
    const u16* buf = lds + cur * 16384;               // 32768 bytes = 16384 u16
    const int pb = (cur == 0) ? 2 : cur - 1;          // (t+2)%3
    const bool pf = (t + 2 < 32);

    // ---- phase 0: B all + A m0-3; stage round 0 of t+2 ----
    bf16x8 bfr[4], af[4];
#pragma unroll
    for (int n = 0; n < 4; ++n) bfr[n] = *(const bf16x8*)(buf + bofr[n]);
#pragma unroll
    for (int m = 0; m < 4; ++m) af[m] = *(const bf16x8*)(buf + aofr[m]);
    if (pf) stage(t + 2, 0, pb * 32768);
    __builtin_amdgcn_s_barrier();
    __builtin_amdgcn_s_setprio(1);
#pragma unroll
    for (int m = 0; m < 4; ++m)
#pragma unroll
      for (int n = 0; n < 4; ++n)
        acc[m][n] = __builtin_amdgcn_mfma_f32_16x16x32_bf16(af[m], bfr[n], acc[m][n], 0, 0, 0);
    __builtin_amdgcn_s_setprio(0);

    // ---- phase 1: A m4-7; stage round 1 of t+2 ----
#pragma unroll
    for (int m = 0; m < 4; ++m) af[m] = *(const bf16x8*)(buf + aofr[4 + m]);
    if (pf) stage(t + 2, 1, pb * 32768);
    __builtin_amdgcn_s_barrier();
    __builtin_amdgcn_s_setprio(1);
#pragma unroll
    for (int m = 0; m < 4; ++m)
#pragma unroll
      for (int n = 0; n < 4; ++n)
        acc[4 + m][n] = __builtin_amdgcn_mfma_f32_16x16x32_bf16(af[m], bfr[n], acc[4 + m][n], 0, 0, 0);
    __builtin_amdgcn_s_setprio(0);

    // ---- tile boundary: counted wait (t+1 complete, t+2 in flight) ----
    if (t < 30) {
      asm volatile("s_waitcnt vmcnt(4)" ::: "memory");
      __builtin_amdgcn_s_barrier();
    } else if (t == 30) {
      asm volatile("s_waitcnt vmcnt(0)" ::: "memory");
      __builtin_amdgcn_s_barrier();
    }
    cur = (cur == 2) ? 0 : cur + 1;
  }

  // ---- epilogue ----
  const int r0 = (lane >> 4) * 4;
  const int c0 = lane & 15;
#pragma unroll
  for (int m = 0; m < 8; ++m) {
#pragma unroll
    for (int n = 0; n < 4; ++n) {
      const int col = n0 + wn * 64 + n * 16 + c0;
      const float bv = bias[col];
      if (OUT_MODE == 3) {
        const int pairI = (col & 1023) >> 1;
        const float sgn = (col & 1) ? 1.f : -1.f;
#pragma unroll
        for (int r = 0; r < 4; ++r) {
          const int row = m0 + wm * 128 + m * 16 + r0 + r;
          const float v = acc[m][n][r] + bv;
          const float p = __shfl_xor(v, 1);
          const float2 cs = ((const float2*)tab)[(row >> 8) * 512 + pairI];
          ((u16*)Cp)[(size_t)row * ldc + col] = f2bf(v * cs.x + sgn * p * cs.y);
        }
      } else {
#pragma unroll
        for (int r = 0; r < 4; ++r) {
          const int row = m0 + wm * 128 + m * 16 + r0 + r;
          const float v = acc[m][n][r] + bv;
          if (OUT_MODE == 0) {
            ((u16*)Cp)[(size_t)row * ldc + col] = f2bf(v);
          } else if (OUT_MODE == 2) {
            ((float*)Cp)[(size_t)row * ldc + col] = v;
          } else {
            const int which = col >> 10, c = col & 1023;
            const int h = c >> 6, d = c & 63;
            const int s = row >> 8, b = row & 255;
            ((u16*)Cp)[(size_t)which * thirdStride +
                       (((size_t)(b * NH + h) * S_LEN + s) * HDIM + d)] = f2bf(v);
          }
        }
      }
    }
  }
}

// ---------------- attention: one block per (b,h) ----------------
__global__ __launch_bounds__(256) void k_attn(const u16* __restrict__ qkv2,
                                              const float* __restrict__ mask,
                                              u16* __restrict__ O1) {
  __shared__ u16 Vt[64 * 128];     // Vt[d][s ^ ((d&7)<<3)]   16KB
  __shared__ u16 Pb[128 * 128];    // Pb[q][s ^ ((q&7)<<3)]   32KB
  __shared__ float redM[2][128];
  __shared__ float redS[2][128];

  const size_t TS = (size_t)MROWS * W_DIM;
  const int bh = blockIdx.x, b = bh >> 4, h = bh & 15;
  const int tid = threadIdx.x, lane = tid & 63, wave = tid >> 6;
  const int wm = wave >> 1, wn = wave & 1;
  const int c0 = lane & 15, hi = lane >> 4;

  const u16* Qg = qkv2 + (size_t)bh * (S_LEN * HDIM);
  const u16* Kg = Qg + TS;
  const u16* Vg = Qg + 2 * TS;

  for (int idx = tid; idx < 1024; idx += 256) {
    const int s = idx >> 3, c = (idx & 7) * 8;
    uint4 vv = make_uint4(0, 0, 0, 0);
    if (s < S_LEN) vv = *(const uint4*)(Vg + (size_t)s * HDIM + c);
    u16 tmp[8];
    *(uint4*)tmp = vv;
#pragma unroll
    for (int j = 0; j < 8; ++j)
      Vt[(c + j) * 128 + (s ^ (j << 3))] = tmp[j];
  }

  f32x4 acc[4][4] = {};
#pragma unroll
  for (int kk = 0; kk < 2; ++kk) {
    bf16x8 af[4], bfr[4];
#pragma unroll
    for (int m = 0; m < 4; ++m)
      af[m] = *(const bf16x8*)(Qg + (size_t)(wm * 64 + m * 16 + c0) * HDIM + kk * 32 + hi * 8);
#pragma unroll
    for (int n = 0; n < 4; ++n)
      bfr[n] = *(const bf16x8*)(Kg + (size_t)(wn * 64 + n * 16 + c0) * HDIM + kk * 32 + hi * 8);
#pragma unroll
    for (int m = 0; m < 4; ++m)
#pragma unroll
      for (int n = 0; n < 4; ++n)
        acc[m][n] = __builtin_amdgcn_mfma_f32_16x16x32_bf16(af[m], bfr[n], acc[m][n], 0, 0, 0);
  }

#pragma unroll
  for (int m = 0; m < 4; ++m)
#pragma unroll
    for (int n = 0; n < 4; ++n) {
      const int col = wn * 64 + n * 16 + c0;
#pragma unroll
      for (int r = 0; r < 4; ++r) {
        const int row = wm * 64 + m * 16 + hi * 4 + r;
        float v = acc[m][n][r] * 0.125f;
        if (col < S_LEN) {
          if (row < S_LEN) v += mask[row * S_LEN + col];
        } else {
          v = -1e30f;
        }
        acc[m][n][r] = v;
      }
    }

  float mx[4][4];
#pragma unroll
  for (int m = 0; m < 4; ++m)
#pragma unroll
    for (int r = 0; r < 4; ++r)
      mx[m][r] = fmaxf(fmaxf(acc[m][0][r], acc[m][1][r]),
                       fmaxf(acc[m][2][r], acc[m][3][r]));
#pragma unroll
  for (int d = 1; d < 16; d <<= 1)
#pragma unroll
    for (int m = 0; m < 4; ++m)
#pragma unroll
      for (int r = 0; r < 4; ++r)
        mx[m][r] = fmaxf(mx[m][r], __shfl_xor(mx[m][r], d));
  if (c0 == 0) {
#pragma unroll
    for (int m = 0; m < 4; ++m)
#pragma unroll
      for (int r = 0; r < 4; ++r)
        redM[wn][wm * 64 + m * 16 + hi * 4 + r] = mx[m][r];
  }
  __syncthreads();

  float ps[4][4];
#pragma unroll
  for (int m = 0; m < 4; ++m)
#pragma unroll
    for (int r = 0; r < 4; ++r) {
      const int row = wm * 64 + m * 16 + hi * 4 + r;
      const float rm = fmaxf(redM[0][row], redM[1][row]);
      float p = 0.f;
#pragma unroll
      for (int n = 0; n < 4; ++n) {
        const float e = __expf(acc[m][n][r] - rm);
        p += e;
        const int col = wn * 64 + n * 16 + c0;
        Pb[row * 128 + (col ^ ((row & 7) << 3))] = f2bf(e);
      }
      ps[m][r] = p;
    }
#pragma unroll
  for (int d = 1; d < 16; d <<= 1)
#pragma unroll
    for (int m = 0; m < 4; ++m)
#pragma unroll
      for (int r = 0; r < 4; ++r)
        ps[m][r] += __shfl_xor(ps[m][r], d);
  if (c0 == 0) {
#pragma unroll
    for (int m = 0; m < 4; ++m)
#pragma unroll
      for (int r = 0; r < 4; ++r)
        redS[wn][wm * 64 + m * 16 + hi * 4 + r] = ps[m][r];
  }
  __syncthreads();

  f32x4 o[4][2] = {};
#pragma unroll
  for (int kk = 0; kk < 4; ++kk) {
    bf16x8 pa[4], vb[2];
#pragma unroll
    for (int m = 0; m < 4; ++m) {
      const int row = wm * 64 + m * 16 + c0;
      pa[m] = *(const bf16x8*)(Pb + row * 128 + ((kk * 32 + hi * 8) ^ ((row & 7) << 3)));
    }
#pragma unroll
    for (int n = 0; n < 2; ++n) {
      const int d = wn * 32 + n * 16 + c0;
      vb[n] = *(const bf16x8*)(Vt + d * 128 + ((kk * 32 + hi * 8) ^ ((d & 7) << 3)));
    }
#pragma unroll
    for (int m = 0; m < 4; ++m)
#pragma unroll
      for (int n = 0; n < 2; ++n)
        o[m][n] = __builtin_amdgcn_mfma_f32_16x16x32_bf16(pa[m], vb[n], o[m][n], 0, 0, 0);
  }

#pragma unroll
  for (int m = 0; m < 4; ++m)
#pragma unroll
    for (int r = 0; r < 4; ++r) {
      const int row = wm * 64 + m * 16 + hi * 4 + r;
      if (row < S_LEN) {
        const float iv = 1.0f / (redS[0][row] + redS[1][row]);
#pragma unroll
        for (int n = 0; n < 2; ++n) {
          const int d = wn * 32 + n * 16 + c0;
          O1[((size_t)row * B_DIM + b) * W_DIM + h * HDIM + d] = f2bf(o[m][n][r] * iv);
        }
      }
    }
}

// ---------------- launcher ----------------
extern "C" void kernel_launch(void* const* d_in, const int* in_sizes, int n_in,
                              void* d_out, int out_size, void* d_ws, size_t ws_size,
                              hipStream_t stream) {
  (void)in_sizes; (void)n_in; (void)out_size; (void)ws_size;
  const float* tensor    = (const float*)d_in[0];
  const float* mask      = (const float*)d_in[1];
  const float* q_w       = (const float*)d_in[2];
  const float* q_b       = (const float*)d_in[3];
  const float* k_w       = (const float*)d_in[4];
  const float* k_b       = (const float*)d_in[5];
  const float* v_w       = (const float*)d_in[6];
  const float* v_b       = (const float*)d_in[7];
  const float* in_proj_w = (const float*)d_in[8];
  const float* in_proj_b = (const float*)d_in[9];
  const float* mha_w     = (const float*)d_in[10];
  const float* mha_b     = (const float*)d_in[11];
  const float* out_w     = (const float*)d_in[12];
  const float* out_b     = (const float*)d_in[13];

  char* ws = (char*)d_ws;
  size_t off = 0;
  auto alloc = [&](size_t bytes) {
    char* p = ws + off;
    off += (bytes + 255) & ~(size_t)255;
    return p;
  };

  const size_t TS = (size_t)MROWS * W_DIM;

  float* tab = (float*)alloc((size_t)S_LEN * 512 * 2 * sizeof(float));
  u16* Xbf   = (u16*)alloc(TS * 2);                          // reused as O1
  u16* qkv1  = (u16*)alloc((size_t)MROWS * 2048 * 2);        // q,k after GEMM1+rope
  u16* qkv2  = (u16*)alloc(TS * 3 * 2);                      // q,k,v head layout
  u16* WC1   = (u16*)alloc((size_t)2048 * 1024 * 2);         // [q_w;k_w] bf16
  u16* W2    = (u16*)alloc((size_t)3072 * 1024 * 2);         // in_proj bf16
  u16* WvT   = (u16*)alloc((size_t)1024 * 1024 * 2);
  u16* WmT   = (u16*)alloc((size_t)1024 * 1024 * 2);
  u16* WO    = (u16*)alloc((size_t)1024 * 1024 * 2);
  u16* WVf   = (u16*)alloc((size_t)1024 * 1024 * 2);         // Wv2 @ Wv
  u16* WFf   = (u16*)alloc((size_t)1024 * 1024 * 2);         // Wo @ Wm
  float* bc1 = (float*)alloc(2048 * sizeof(float));
  float* bvf = (float*)alloc(1024 * sizeof(float));
  float* bff = (float*)alloc(1024 * sizeof(float));
  float* zb  = (float*)alloc(1024 * sizeof(float));
  u16* O1 = Xbf;  // X dead after GEMM_v

  // ---- prep / converts ----
  k_rope_tab<<<dim3((S_LEN * 512 + 255) / 256), 256, 0, stream>>>(tab);
  k_cvt<<<dim3(MROWS * W_DIM / 4 / 256), 256, 0, stream>>>(tensor, Xbf, MROWS * W_DIM / 4);
  k_cvt<<<dim3(1024), 256, 0, stream>>>(q_w, WC1, 262144);
  k_cvt<<<dim3(1024), 256, 0, stream>>>(k_w, WC1 + 1048576, 262144);
  k_cvt<<<dim3(3072), 256, 0, stream>>>(in_proj_w, W2, 786432);
  k_cvt<<<dim3(1024), 256, 0, stream>>>(out_w, WO, 262144);
  k_cvt_t<<<dim3(32, 32), dim3(32, 8), 0, stream>>>(v_w, WvT);
  k_cvt_t<<<dim3(32, 32), dim3(32, 8), 0, stream>>>(mha_w, WmT);
  k_bias2<<<dim3(8), 256, 0, stream>>>(q_b, k_b, bc1);
  k_zero<<<dim3(4), 256, 0, stream>>>(zb, 1024);
  k_biasfold<<<dim3(256), 256, 0, stream>>>(in_proj_w + (size_t)2048 * 1024, v_b,
                                            in_proj_b + 2048, bvf);
  k_biasfold<<<dim3(256), 256, 0, stream>>>(out_w, mha_b, out_b, bff);

  // ---- weight folds (1024^3 bf16 GEMMs, small kernel) ----
  k_gemm<0, 0><<<dim3(8, 8), 256, 0, stream>>>(
      W2 + (size_t)2048 * 1024, 1024, WvT, zb, WVf, 1024, 1024, 0, nullptr);
  k_gemm<0, 0><<<dim3(8, 8), 256, 0, stream>>>(
      WO, 1024, WmT, zb, WFf, 1024, 1024, 0, nullptr);

  // ---- GEMM1 + fused rope: X @ [q_w;k_w]^T + bias -> qkv1 (24832 x 2048) ----
  k_gemm256<3, 0><<<dim3(97 * 8), 512, 0, stream>>>(
      Xbf, W_DIM, WC1, bc1, qkv1, 2048, 0, tab, 8);

  // ---- v path (folded): X @ WVf^T + bvf -> v heads ----
  k_gemm256<1, 0><<<dim3(97 * 4), 512, 0, stream>>>(
      Xbf, W_DIM, WVf, bvf, qkv2 + 2 * TS, 0, TS, nullptr, 4);

  // ---- GEMM2 (block-diagonal): qkv1 @ [Wq2;Wk2]^T + b -> q,k heads ----
  k_gemm256<1, 1><<<dim3(97 * 8), 512, 0, stream>>>(
      qkv1, 2048, W2, in_proj_b, qkv2, 0, TS, nullptr, 8);

  // ---- attention ----
  k_attn<<<dim3(B_DIM * NH), 256, 0, stream>>>(qkv2, mask, O1);

  // ---- output (folded): O1 @ WFf^T + bff -> d_out (fp32) ----
  k_gemm256<2, 0><<<dim3(97 * 4), 512, 0, stream>>>(
      O1, W_DIM, WFf, bff, d_out, W_DIM, 0, nullptr, 4);
}

// Round 5
// 658.129 us; speedup vs baseline: 1.6708x; 1.0876x over previous
//
#include <hip/hip_runtime.h>
#include <cstdint>
#include <cstddef>

#define S_LEN 97
#define B_DIM 256
#define W_DIM 1024
#define NH    16
#define HDIM  64
#define MROWS (S_LEN * B_DIM)   // 24832 = 97*256

typedef unsigned short u16;
typedef __bf16 bf16x8 __attribute__((ext_vector_type(8)));
typedef float  f32x4  __attribute__((ext_vector_type(4)));

__device__ __forceinline__ u16 f2bf(float f) {
  union { float f; uint32_t u; } v; v.f = f;
  uint32_t u = v.u;
  return (u16)((u + 0x7FFFu + ((u >> 16) & 1u)) >> 16);  // RNE
}
__device__ __forceinline__ float bf2f(u16 h) {
  union { uint32_t u; float f; } v; v.u = ((uint32_t)h) << 16;
  return v.f;
}

// async global->LDS, 16B per lane. LDS dest must be wave-uniform base; HW adds lane*16.
__device__ __forceinline__ void gload16(const void* g, void* lds) {
  __builtin_amdgcn_global_load_lds(
      (const __attribute__((address_space(1))) void*)(uintptr_t)g,
      (__attribute__((address_space(3))) void*)(uint32_t)(uintptr_t)lds,
      16, 0, 0);
}

// ---------------- prep kernels ----------------
__global__ void k_cvt(const float* __restrict__ s, u16* __restrict__ d, int n4) {
  int i = blockIdx.x * blockDim.x + threadIdx.x;
  if (i >= n4) return;
  float4 v = ((const float4*)s)[i];
  uint2 pk;
  pk.x = (uint32_t)f2bf(v.x) | ((uint32_t)f2bf(v.y) << 16);
  pk.y = (uint32_t)f2bf(v.z) | ((uint32_t)f2bf(v.w) << 16);
  ((uint2*)d)[i] = pk;
}

// dst = src^T (1024x1024), fp32 -> bf16
__global__ void k_cvt_t(const float* __restrict__ src, u16* __restrict__ dst) {
  __shared__ float t[32][33];
  const int bx = blockIdx.x * 32, by = blockIdx.y * 32;
  const int tx = threadIdx.x, ty = threadIdx.y;  // 32 x 8
  for (int yy = ty; yy < 32; yy += 8)
    t[yy][tx] = src[(size_t)(by + yy) * 1024 + bx + tx];
  __syncthreads();
  for (int yy = ty; yy < 32; yy += 8)
    dst[(size_t)(bx + yy) * 1024 + by + tx] = f2bf(t[tx][yy]);
}

__global__ void k_bias2(const float* a, const float* b, float* dst) {
  int i = blockIdx.x * blockDim.x + threadIdx.x;
  if (i >= 2 * W_DIM) return;
  dst[i] = (i < W_DIM) ? a[i] : b[i - W_DIM];
}

__global__ void k_zero(float* dst, int n) {
  int i = blockIdx.x * blockDim.x + threadIdx.x;
  if (i < n) dst[i] = 0.f;
}

// padded mask: maskP[r][c] = mask[r][c] (r,c<97), -1e30 for c>=97, 0 for r>=97
__global__ void k_maskpad(const float* __restrict__ mask, float* __restrict__ mp) {
  int i = blockIdx.x * blockDim.x + threadIdx.x;  // 0..16383
  int r = i >> 7, c = i & 127;
  float v;
  if (c >= S_LEN) v = -1e30f;
  else if (r < S_LEN) v = mask[r * S_LEN + c];
  else v = 0.f;
  mp[i] = v;
}

// out[row] = dot(M[row,:], v) + b2[row]   (M: 1024x1024 fp32)
__global__ void k_biasfold(const float* __restrict__ M, const float* __restrict__ v,
                           const float* __restrict__ b2, float* __restrict__ out) {
  const int lane = threadIdx.x & 63, wave = threadIdx.x >> 6;
  const int row = blockIdx.x * 4 + wave;
  float s = 0.f;
  for (int k = lane; k < 1024; k += 64) s += M[(size_t)row * 1024 + k] * v[k];
#pragma unroll
  for (int d = 32; d; d >>= 1) s += __shfl_xor(s, d);
  if (lane == 0) out[row] = s + b2[row];
}

__global__ void k_rope_tab(float* __restrict__ tab) {
  int idx = blockIdx.x * blockDim.x + threadIdx.x;
  if (idx >= S_LEN * 512) return;
  int s = idx / 512, i = idx % 512;
  float freq = expf(-(float)i * (9.210340371976184f / 512.0f));
  float ang = (float)s * freq;
  float sv, cv;
  sincosf(ang, &sv, &cv);
  tab[idx * 2 + 0] = cv;
  tab[idx * 2 + 1] = sv;
}

// ---------------- small 128x128 GEMM (weight folds only) ----------------
template <int OUT_MODE, int ACOLB>
__global__ __launch_bounds__(256) void k_gemm(
    const u16* __restrict__ A, int lda, const u16* __restrict__ Bw,
    const float* __restrict__ bias, void* __restrict__ Cp, int ldc, int K,
    size_t thirdStride, const float* __restrict__ tab) {
  __shared__ u16 As[128 * 64];
  __shared__ u16 Bs[128 * 64];

  const int tid = threadIdx.x, lane = tid & 63, wave = tid >> 6;
  const int wm = wave >> 1, wn = wave & 1;
  const int m0 = blockIdx.y * 128;
  const int n0 = blockIdx.x * 128;
  const int aoff = ACOLB ? (n0 & ~1023) : 0;

  f32x4 acc[4][4] = {};

  const int lrow = lane >> 3;
  const int lcol = (lane & 7) * 8;
  const u16* Ag = A + (size_t)(m0 + wave * 8 + lrow) * lda + aoff + lcol;
  const u16* Bg = Bw + (size_t)(n0 + wave * 8 + lrow) * K + lcol;
  u16* Asl = As + wave * 8 * 64;
  u16* Bsl = Bs + wave * 8 * 64;

  for (int kt = 0; kt < K; kt += 64) {
#pragma unroll
    for (int i = 0; i < 4; ++i) {
      gload16(Ag + (size_t)(i * 32) * lda + kt, Asl + i * 2048);
      gload16(Bg + (size_t)(i * 32) * K + kt, Bsl + i * 2048);
    }
    __syncthreads();
#pragma unroll
    for (int kk = 0; kk < 2; ++kk) {
      bf16x8 af[4], bfr[4];
#pragma unroll
      for (int m = 0; m < 4; ++m)
        af[m] = *(const bf16x8*)(As + (wm * 64 + m * 16 + (lane & 15)) * 64 + kk * 32 + (lane >> 4) * 8);
#pragma unroll
      for (int n = 0; n < 4; ++n)
        bfr[n] = *(const bf16x8*)(Bs + (wn * 64 + n * 16 + (lane & 15)) * 64 + kk * 32 + (lane >> 4) * 8);
#pragma unroll
      for (int m = 0; m < 4; ++m)
#pragma unroll
        for (int n = 0; n < 4; ++n)
          acc[m][n] = __builtin_amdgcn_mfma_f32_16x16x32_bf16(af[m], bfr[n], acc[m][n], 0, 0, 0);
    }
    __syncthreads();
  }

  const int r0 = (lane >> 4) * 4;
  const int c0 = lane & 15;
#pragma unroll
  for (int m = 0; m < 4; ++m) {
#pragma unroll
    for (int n = 0; n < 4; ++n) {
      const int col = n0 + wn * 64 + n * 16 + c0;
      const float bv = bias[col];
#pragma unroll
      for (int r = 0; r < 4; ++r) {
        const int row = m0 + wm * 64 + m * 16 + r0 + r;
        const float v = acc[m][n][r] + bv;
        if (OUT_MODE == 0) {
          ((u16*)Cp)[(size_t)row * ldc + col] = f2bf(v);
        } else if (OUT_MODE == 2) {
          ((float*)Cp)[(size_t)row * ldc + col] = v;
        }
      }
    }
  }
  (void)thirdStride; (void)tab;
}

// ---------------- 256x256 pipelined GEMM (K=1024 fixed) ----------------
// 8 waves (2M x 4N), per-wave 128x64. BK=32, 32 K-tiles.
// 3 LDS buffers, depth-2 prefetch, counted vmcnt(4) (T3/T4). Chunk-XOR swizzle (T2).
// setprio around MFMA (T5). Bijective XCD grid swizzle (T1).
// OUT_MODE: 0 bf16 row-major, 1 qkv-head scatter, 2 f32 row-major, 3 bf16+rope
// SCALEQ: scale cols [0,1024) by 0.125 in head-scatter mode (softmax scale fold)
template <int OUT_MODE, int ACOLB, int SCALEQ = 0>
__global__ __launch_bounds__(512, 2) void k_gemm256(
    const u16* __restrict__ A, int lda, const u16* __restrict__ Bw,
    const float* __restrict__ bias, void* __restrict__ Cp, int ldc,
    size_t thirdStride, const float* __restrict__ tab, int Nt) {
  __shared__ u16 lds[3 * 16384];  // 3 x (A 16KB + B 16KB) = 96KB

  const int tid = threadIdx.x, lane = tid & 63, wave = tid >> 6;
  const int wm = wave >> 2, wn = wave & 3;

  // bijective XCD swizzle (m204), n-tile inner
  const int nwg = gridDim.x;
  const int qq = nwg >> 3, rr_ = nwg & 7;
  const int xcd = blockIdx.x & 7, sub = blockIdx.x >> 3;
  const int seq = (xcd < rr_ ? xcd * (qq + 1) : rr_ * (qq + 1) + (xcd - rr_) * qq) + sub;
  const int mt = seq / Nt, nt = seq - mt * Nt;
  const int m0 = mt * 256, n0 = nt * 256;
  const int aoff = ACOLB ? (n0 & ~1023) : 0;

  const int srow = lane >> 2;
  const int lch = (lane & 3) ^ (srow & 3);
  const u16* agb[2]; const u16* bgb[2];
  uint32_t aldsb[2], bldsb[2];
#pragma unroll
  for (int rr = 0; rr < 2; ++rr) {
    const int row = (rr * 8 + wave) * 16 + srow;
    agb[rr] = A + (size_t)(m0 + row) * lda + aoff + lch * 8;
    bgb[rr] = Bw + (size_t)(n0 + row) * 1024 + lch * 8;
    aldsb[rr] = (uint32_t)((rr * 8 + wave) * 1024);
    bldsb[rr] = (uint32_t)(16384 + (rr * 8 + wave) * 1024);
  }

  auto stage = [&](int t, int rr, int cbytes) {
    gload16(agb[rr] + t * 32, (char*)lds + cbytes + aldsb[rr]);
    gload16(bgb[rr] + t * 32, (char*)lds + cbytes + bldsb[rr]);
  };

  const int chunkoff = ((lane >> 4) ^ (lane & 3)) * 8;
  int aofr[8], bofr[4];
#pragma unroll
  for (int m = 0; m < 8; ++m)
    aofr[m] = (wm * 128 + m * 16 + (lane & 15)) * 32 + chunkoff;
#pragma unroll
  for (int n = 0; n < 4; ++n)
    bofr[n] = 8192 + (wn * 64 + n * 16 + (lane & 15)) * 32 + chunkoff;

#pragma unroll
  for (int t = 0; t < 2; ++t) {
    stage(t, 0, t * 32768);
    stage(t, 1, t * 32768);
  }
  asm volatile("s_waitcnt vmcnt(4)" ::: "memory");
  __builtin_amdgcn_s_barrier();

  f32x4 acc[8][4] = {};
  int cur = 0;
  for (int t = 0; t < 32; ++t) {
    const u16* buf = lds + cur * 16384;
    const int pb = (cur == 0) ? 2 : cur - 1;
    const bool pf = (t + 2 < 32);

    bf16x8 bfr[4], af[4];
#pragma unroll
    for (int n = 0; n < 4; ++n) bfr[n] = *(const bf16x8*)(buf + bofr[n]);
#pragma unroll
    for (int m = 0; m < 4; ++m) af[m] = *(const bf16x8*)(buf + aofr[m]);
    if (pf) stage(t + 2, 0, pb * 32768);
    __builtin_amdgcn_s_barrier();
    __builtin_amdgcn_s_setprio(1);
#pragma unroll
    for (int m = 0; m < 4; ++m)
#pragma unroll
      for (int n = 0; n < 4; ++n)
        acc[m][n] = __builtin_amdgcn_mfma_f32_16x16x32_bf16(af[m], bfr[n], acc[m][n], 0, 0, 0);
    __builtin_amdgcn_s_setprio(0);

#pragma unroll
    for (int m = 0; m < 4; ++m) af[m] = *(const bf16x8*)(buf + aofr[4 + m]);
    if (pf) stage(t + 2, 1, pb * 32768);
    __builtin_amdgcn_s_barrier();
    __builtin_amdgcn_s_setprio(1);
#pragma unroll
    for (int m = 0; m < 4; ++m)
#pragma unroll
      for (int n = 0; n < 4; ++n)
        acc[4 + m][n] = __builtin_amdgcn_mfma_f32_16x16x32_bf16(af[m], bfr[n], acc[4 + m][n], 0, 0, 0);
    __builtin_amdgcn_s_setprio(0);

    if (t < 30) {
      asm volatile("s_waitcnt vmcnt(4)" ::: "memory");
      __builtin_amdgcn_s_barrier();
    } else if (t == 30) {
      asm volatile("s_waitcnt vmcnt(0)" ::: "memory");
      __builtin_amdgcn_s_barrier();
    }
    cur = (cur == 2) ? 0 : cur + 1;
  }

  const int r0 = (lane >> 4) * 4;
  const int c0 = lane & 15;
#pragma unroll
  for (int m = 0; m < 8; ++m) {
#pragma unroll
    for (int n = 0; n < 4; ++n) {
      const int col = n0 + wn * 64 + n * 16 + c0;
      const float bv = bias[col];
      if (OUT_MODE == 3) {
        const int pairI = (col & 1023) >> 1;
        const float sgn = (col & 1) ? 1.f : -1.f;
#pragma unroll
        for (int r = 0; r < 4; ++r) {
          const int row = m0 + wm * 128 + m * 16 + r0 + r;
          const float v = acc[m][n][r] + bv;
          const float p = __shfl_xor(v, 1);
          const float2 cs = ((const float2*)tab)[(row >> 8) * 512 + pairI];
          ((u16*)Cp)[(size_t)row * ldc + col] = f2bf(v * cs.x + sgn * p * cs.y);
        }
      } else {
#pragma unroll
        for (int r = 0; r < 4; ++r) {
          const int row = m0 + wm * 128 + m * 16 + r0 + r;
          const float v = acc[m][n][r] + bv;
          if (OUT_MODE == 0) {
            ((u16*)Cp)[(size_t)row * ldc + col] = f2bf(v);
          } else if (OUT_MODE == 2) {
            ((float*)Cp)[(size_t)row * ldc + col] = v;
          } else {
            const int which = col >> 10, c = col & 1023;
            const int h = c >> 6, d = c & 63;
            const int s = row >> 8, b = row & 255;
            const float sc = (SCALEQ && which == 0) ? 0.125f : 1.0f;
            ((u16*)Cp)[(size_t)which * thirdStride +
                       (((size_t)(b * NH + h) * S_LEN + s) * HDIM + d)] = f2bf(v * sc);
          }
        }
      }
    }
  }
}

// ---------------- attention: one block (512 thr, 8 waves) per (b,h) ----------------
// QK^T: wave = (wm2: 64q) x (wn4: 32k). PV: wave = (wm2: 64q) x (wn4: 16d).
// maskP pre-padded (col>=97 -> -1e30). q pre-scaled by 0.125 in GEMM2 epilogue.
__global__ __launch_bounds__(512, 6) void k_attn(const u16* __restrict__ qkv2,
                                                 const float* __restrict__ maskP,
                                                 u16* __restrict__ O1) {
  __shared__ u16 Vt[64 * 128];     // Vt[d][s ^ ((d&7)<<3)]   16KB
  __shared__ u16 Pb[128 * 128];    // Pb[q][s ^ ((q&7)<<3)]   32KB
  __shared__ float redM[4][128];
  __shared__ float redS[4][128];

  const size_t TS = (size_t)MROWS * W_DIM;
  const int bh = blockIdx.x, b = bh >> 4, h = bh & 15;
  const int tid = threadIdx.x, lane = tid & 63, wave = tid >> 6;
  const int wm = wave >> 2;        // 0..1  (64 q-rows)
  const int wn = wave & 3;         // 0..3
  const int c0 = lane & 15, hi = lane >> 4;

  const u16* Qg = qkv2 + (size_t)bh * (S_LEN * HDIM);
  const u16* Kg = Qg + TS;
  const u16* Vg = Qg + 2 * TS;

  // ---- stage V transposed into swizzled Vt (zero-pad s>=97) ----
  for (int idx = tid; idx < 1024; idx += 512) {
    const int s = idx >> 3, c = (idx & 7) * 8;
    uint4 vv = make_uint4(0, 0, 0, 0);
    if (s < S_LEN) vv = *(const uint4*)(Vg + (size_t)s * HDIM + c);
    u16 tmp[8];
    *(uint4*)tmp = vv;
#pragma unroll
    for (int j = 0; j < 8; ++j)
      Vt[(c + j) * 128 + (s ^ (j << 3))] = tmp[j];
  }

  // ---- QK^T: 64q x 32k per wave, fragments straight from global ----
  f32x4 acc[4][2] = {};
#pragma unroll
  for (int kk = 0; kk < 2; ++kk) {
    bf16x8 af[4], bfr[2];
#pragma unroll
    for (int m = 0; m < 4; ++m)
      af[m] = *(const bf16x8*)(Qg + (size_t)(wm * 64 + m * 16 + c0) * HDIM + kk * 32 + hi * 8);
#pragma unroll
    for (int n = 0; n < 2; ++n)
      bfr[n] = *(const bf16x8*)(Kg + (size_t)(wn * 32 + n * 16 + c0) * HDIM + kk * 32 + hi * 8);
#pragma unroll
    for (int m = 0; m < 4; ++m)
#pragma unroll
      for (int n = 0; n < 2; ++n)
        acc[m][n] = __builtin_amdgcn_mfma_f32_16x16x32_bf16(af[m], bfr[n], acc[m][n], 0, 0, 0);
  }

  // ---- mask add + row max (per-m to keep live ranges short) ----
#pragma unroll
  for (int m = 0; m < 4; ++m) {
    float mxm[4];
#pragma unroll
    for (int r = 0; r < 4; ++r) {
      const int row = wm * 64 + m * 16 + hi * 4 + r;
#pragma unroll
      for (int n = 0; n < 2; ++n)
        acc[m][n][r] += maskP[row * 128 + wn * 32 + n * 16 + c0];
      mxm[r] = fmaxf(acc[m][0][r], acc[m][1][r]);
    }
#pragma unroll
    for (int d = 1; d < 16; d <<= 1)
#pragma unroll
      for (int r = 0; r < 4; ++r)
        mxm[r] = fmaxf(mxm[r], __shfl_xor(mxm[r], d));
    if (c0 == 0) {
#pragma unroll
      for (int r = 0; r < 4; ++r)
        redM[wn][wm * 64 + m * 16 + hi * 4 + r] = mxm[r];
    }
  }
  __syncthreads();   // redM ready; also fences Vt staging

  // ---- exp, partial sums, write P (bf16, swizzled) ----
#pragma unroll
  for (int m = 0; m < 4; ++m) {
    float psm[4];
#pragma unroll
    for (int r = 0; r < 4; ++r) {
      const int row = wm * 64 + m * 16 + hi * 4 + r;
      const float rm = fmaxf(fmaxf(redM[0][row], redM[1][row]),
                             fmaxf(redM[2][row], redM[3][row]));
      float p = 0.f;
#pragma unroll
      for (int n = 0; n < 2; ++n) {
        const float e = __expf(acc[m][n][r] - rm);
        p += e;
        const int col = wn * 32 + n * 16 + c0;
        Pb[row * 128 + (col ^ ((row & 7) << 3))] = f2bf(e);
      }
      psm[r] = p;
    }
#pragma unroll
    for (int d = 1; d < 16; d <<= 1)
#pragma unroll
      for (int r = 0; r < 4; ++r)
        psm[r] += __shfl_xor(psm[r], d);
    if (c0 == 0) {
#pragma unroll
      for (int r = 0; r < 4; ++r)
        redS[wn][wm * 64 + m * 16 + hi * 4 + r] = psm[r];
    }
  }
  __syncthreads();   // Pb + redS ready

  // ---- PV: 64q x 16d per wave ----
  f32x4 o[4] = {};
#pragma unroll
  for (int kk = 0; kk < 4; ++kk) {
    bf16x8 pa[4], vb;
#pragma unroll
    for (int m = 0; m < 4; ++m) {
      const int row = wm * 64 + m * 16 + c0;
      pa[m] = *(const bf16x8*)(Pb + row * 128 + ((kk * 32 + hi * 8) ^ ((row & 7) << 3)));
    }
    {
      const int d = wn * 16 + c0;
      vb = *(const bf16x8*)(Vt + d * 128 + ((kk * 32 + hi * 8) ^ ((d & 7) << 3)));
    }
#pragma unroll
    for (int m = 0; m < 4; ++m)
      o[m] = __builtin_amdgcn_mfma_f32_16x16x32_bf16(pa[m], vb, o[m], 0, 0, 0);
  }

#pragma unroll
  for (int m = 0; m < 4; ++m)
#pragma unroll
    for (int r = 0; r < 4; ++r) {
      const int row = wm * 64 + m * 16 + hi * 4 + r;
      if (row < S_LEN) {
        const float iv = 1.0f / (redS[0][row] + redS[1][row] + redS[2][row] + redS[3][row]);
        const int d = wn * 16 + c0;
        O1[((size_t)row * B_DIM + b) * W_DIM + h * HDIM + d] = f2bf(o[m][r] * iv);
      }
    }
}

// ---------------- launcher ----------------
extern "C" void kernel_launch(void* const* d_in, const int* in_sizes, int n_in,
                              void* d_out, int out_size, void* d_ws, size_t ws_size,
                              hipStream_t stream) {
  (void)in_sizes; (void)n_in; (void)out_size; (void)ws_size;
  const float* tensor    = (const float*)d_in[0];
  const float* mask      = (const float*)d_in[1];
  const float* q_w       = (const float*)d_in[2];
  const float* q_b       = (const float*)d_in[3];
  const float* k_w       = (const float*)d_in[4];
  const float* k_b       = (const float*)d_in[5];
  const float* v_w       = (const float*)d_in[6];
  const float* v_b       = (const float*)d_in[7];
  const float* in_proj_w = (const float*)d_in[8];
  const float* in_proj_b = (const float*)d_in[9];
  const float* mha_w     = (const float*)d_in[10];
  const float* mha_b     = (const float*)d_in[11];
  const float* out_w     = (const float*)d_in[12];
  const float* out_b     = (const float*)d_in[13];

  char* ws = (char*)d_ws;
  size_t off = 0;
  auto alloc = [&](size_t bytes) {
    char* p = ws + off;
    off += (bytes + 255) & ~(size_t)255;
    return p;
  };

  const size_t TS = (size_t)MROWS * W_DIM;

  float* tab = (float*)alloc((size_t)S_LEN * 512 * 2 * sizeof(float));
  float* maskP = (float*)alloc((size_t)128 * 128 * sizeof(float));
  u16* Xbf   = (u16*)alloc(TS * 2);                          // reused as O1
  u16* qkv1  = (u16*)alloc((size_t)MROWS * 2048 * 2);        // q,k after GEMM1+rope
  u16* qkv2  = (u16*)alloc(TS * 3 * 2);                      // q,k,v head layout
  u16* WC1   = (u16*)alloc((size_t)2048 * 1024 * 2);         // [q_w;k_w] bf16
  u16* W2    = (u16*)alloc((size_t)3072 * 1024 * 2);         // in_proj bf16
  u16* WvT   = (u16*)alloc((size_t)1024 * 1024 * 2);
  u16* WmT   = (u16*)alloc((size_t)1024 * 1024 * 2);
  u16* WO    = (u16*)alloc((size_t)1024 * 1024 * 2);
  u16* WVf   = (u16*)alloc((size_t)1024 * 1024 * 2);         // Wv2 @ Wv
  u16* WFf   = (u16*)alloc((size_t)1024 * 1024 * 2);         // Wo @ Wm
  float* bc1 = (float*)alloc(2048 * sizeof(float));
  float* bvf = (float*)alloc(1024 * sizeof(float));
  float* bff = (float*)alloc(1024 * sizeof(float));
  float* zb  = (float*)alloc(1024 * sizeof(float));
  u16* O1 = Xbf;  // X dead after GEMM_v

  // ---- prep / converts ----
  k_rope_tab<<<dim3((S_LEN * 512 + 255) / 256), 256, 0, stream>>>(tab);
  k_maskpad<<<dim3(64), 256, 0, stream>>>(mask, maskP);
  k_cvt<<<dim3(MROWS * W_DIM / 4 / 256), 256, 0, stream>>>(tensor, Xbf, MROWS * W_DIM / 4);
  k_cvt<<<dim3(1024), 256, 0, stream>>>(q_w, WC1, 262144);
  k_cvt<<<dim3(1024), 256, 0, stream>>>(k_w, WC1 + 1048576, 262144);
  k_cvt<<<dim3(3072), 256, 0, stream>>>(in_proj_w, W2, 786432);
  k_cvt<<<dim3(1024), 256, 0, stream>>>(out_w, WO, 262144);
  k_cvt_t<<<dim3(32, 32), dim3(32, 8), 0, stream>>>(v_w, WvT);
  k_cvt_t<<<dim3(32, 32), dim3(32, 8), 0, stream>>>(mha_w, WmT);
  k_bias2<<<dim3(8), 256, 0, stream>>>(q_b, k_b, bc1);
  k_zero<<<dim3(4), 256, 0, stream>>>(zb, 1024);
  k_biasfold<<<dim3(256), 256, 0, stream>>>(in_proj_w + (size_t)2048 * 1024, v_b,
                                            in_proj_b + 2048, bvf);
  k_biasfold<<<dim3(256), 256, 0, stream>>>(out_w, mha_b, out_b, bff);

  // ---- weight folds (1024^3 bf16 GEMMs, small kernel) ----
  k_gemm<0, 0><<<dim3(8, 8), 256, 0, stream>>>(
      W2 + (size_t)2048 * 1024, 1024, WvT, zb, WVf, 1024, 1024, 0, nullptr);
  k_gemm<0, 0><<<dim3(8, 8), 256, 0, stream>>>(
      WO, 1024, WmT, zb, WFf, 1024, 1024, 0, nullptr);

  // ---- GEMM1 + fused rope: X @ [q_w;k_w]^T + bias -> qkv1 (24832 x 2048) ----
  k_gemm256<3, 0><<<dim3(97 * 8), 512, 0, stream>>>(
      Xbf, W_DIM, WC1, bc1, qkv1, 2048, 0, tab, 8);

  // ---- v path (folded): X @ WVf^T + bvf -> v heads ----
  k_gemm256<1, 0><<<dim3(97 * 4), 512, 0, stream>>>(
      Xbf, W_DIM, WVf, bvf, qkv2 + 2 * TS, 0, TS, nullptr, 4);

  // ---- GEMM2 (block-diagonal): qkv1 @ [Wq2;Wk2]^T + b -> q,k heads (q scaled 1/8) ----
  k_gemm256<1, 1, 1><<<dim3(97 * 8), 512, 0, stream>>>(
      qkv1, 2048, W2, in_proj_b, qkv2, 0, TS, nullptr, 8);

  // ---- attention ----
  k_attn<<<dim3(B_DIM * NH), 512, 0, stream>>>(qkv2, maskP, O1);

  // ---- output (folded): O1 @ WFf^T + bff -> d_out (fp32) ----
  k_gemm256<2, 0><<<dim3(97 * 4), 512, 0, stream>>>(
      O1, W_DIM, WFf, bff, d_out, W_DIM, 0, nullptr, 4);
}

// Round 6
// 614.739 us; speedup vs baseline: 1.7888x; 1.0706x over previous
//
#include <hip/hip_runtime.h>
#include <cstdint>
#include <cstddef>

#define S_LEN 97
#define B_DIM 256
#define W_DIM 1024
#define NH    16
#define HDIM  64
#define MROWS (S_LEN * B_DIM)   // 24832 = 97*256

typedef unsigned short u16;
typedef __bf16 bf16x8 __attribute__((ext_vector_type(8)));
typedef float  f32x4  __attribute__((ext_vector_type(4)));

__device__ __forceinline__ u16 f2bf(float f) {
  union { float f; uint32_t u; } v; v.f = f;
  uint32_t u = v.u;
  return (u16)((u + 0x7FFFu + ((u >> 16) & 1u)) >> 16);  // RNE
}
__device__ __forceinline__ float bf2f(u16 h) {
  union { uint32_t u; float f; } v; v.u = ((uint32_t)h) << 16;
  return v.f;
}

// async global->LDS, 16B per lane. LDS dest must be wave-uniform base; HW adds lane*16.
__device__ __forceinline__ void gload16(const void* g, void* lds) {
  __builtin_amdgcn_global_load_lds(
      (const __attribute__((address_space(1))) void*)(uintptr_t)g,
      (__attribute__((address_space(3))) void*)(uint32_t)(uintptr_t)lds,
      16, 0, 0);
}

// ---------------- prep kernels ----------------
__global__ void k_cvt(const float* __restrict__ s, u16* __restrict__ d, int n4) {
  int i = blockIdx.x * blockDim.x + threadIdx.x;
  if (i >= n4) return;
  float4 v = ((const float4*)s)[i];
  uint2 pk;
  pk.x = (uint32_t)f2bf(v.x) | ((uint32_t)f2bf(v.y) << 16);
  pk.y = (uint32_t)f2bf(v.z) | ((uint32_t)f2bf(v.w) << 16);
  ((uint2*)d)[i] = pk;
}

// dst = src^T (1024x1024), fp32 -> bf16
__global__ void k_cvt_t(const float* __restrict__ src, u16* __restrict__ dst) {
  __shared__ float t[32][33];
  const int bx = blockIdx.x * 32, by = blockIdx.y * 32;
  const int tx = threadIdx.x, ty = threadIdx.y;  // 32 x 8
  for (int yy = ty; yy < 32; yy += 8)
    t[yy][tx] = src[(size_t)(by + yy) * 1024 + bx + tx];
  __syncthreads();
  for (int yy = ty; yy < 32; yy += 8)
    dst[(size_t)(bx + yy) * 1024 + by + tx] = f2bf(t[tx][yy]);
}

__global__ void k_bias2(const float* a, const float* b, float* dst) {
  int i = blockIdx.x * blockDim.x + threadIdx.x;
  if (i >= 2 * W_DIM) return;
  dst[i] = (i < W_DIM) ? a[i] : b[i - W_DIM];
}

__global__ void k_zero(float* dst, int n) {
  int i = blockIdx.x * blockDim.x + threadIdx.x;
  if (i < n) dst[i] = 0.f;
}

// padded mask: maskP[r][c] = mask[r][c] (r,c<97), -1e30 for c>=97, 0 for r>=97
__global__ void k_maskpad(const float* __restrict__ mask, float* __restrict__ mp) {
  int i = blockIdx.x * blockDim.x + threadIdx.x;  // 0..16383
  int r = i >> 7, c = i & 127;
  float v;
  if (c >= S_LEN) v = -1e30f;
  else if (r < S_LEN) v = mask[r * S_LEN + c];
  else v = 0.f;
  mp[i] = v;
}

// out[row] = dot(M[row,:], v) + b2[row]   (M: 1024x1024 fp32)
__global__ void k_biasfold(const float* __restrict__ M, const float* __restrict__ v,
                           const float* __restrict__ b2, float* __restrict__ out) {
  const int lane = threadIdx.x & 63, wave = threadIdx.x >> 6;
  const int row = blockIdx.x * 4 + wave;
  float s = 0.f;
  for (int k = lane; k < 1024; k += 64) s += M[(size_t)row * 1024 + k] * v[k];
#pragma unroll
  for (int d = 32; d; d >>= 1) s += __shfl_xor(s, d);
  if (lane == 0) out[row] = s + b2[row];
}

__global__ void k_rope_tab(float* __restrict__ tab) {
  int idx = blockIdx.x * blockDim.x + threadIdx.x;
  if (idx >= S_LEN * 512) return;
  int s = idx / 512, i = idx % 512;
  float freq = expf(-(float)i * (9.210340371976184f / 512.0f));
  float ang = (float)s * freq;
  float sv, cv;
  sincosf(ang, &sv, &cv);
  tab[idx * 2 + 0] = cv;
  tab[idx * 2 + 1] = sv;
}

// ---------------- small 128x128 GEMM (weight folds only) ----------------
template <int OUT_MODE>
__global__ __launch_bounds__(256) void k_gemm(
    const u16* __restrict__ A, int lda, const u16* __restrict__ Bw,
    const float* __restrict__ bias, void* __restrict__ Cp, int ldc, int K) {
  __shared__ u16 As[128 * 64];
  __shared__ u16 Bs[128 * 64];

  const int tid = threadIdx.x, lane = tid & 63, wave = tid >> 6;
  const int wm = wave >> 1, wn = wave & 1;
  const int m0 = blockIdx.y * 128;
  const int n0 = blockIdx.x * 128;

  f32x4 acc[4][4] = {};

  const int lrow = lane >> 3;
  const int lcol = (lane & 7) * 8;
  const u16* Ag = A + (size_t)(m0 + wave * 8 + lrow) * lda + lcol;
  const u16* Bg = Bw + (size_t)(n0 + wave * 8 + lrow) * K + lcol;
  u16* Asl = As + wave * 8 * 64;
  u16* Bsl = Bs + wave * 8 * 64;

  for (int kt = 0; kt < K; kt += 64) {
#pragma unroll
    for (int i = 0; i < 4; ++i) {
      gload16(Ag + (size_t)(i * 32) * lda + kt, Asl + i * 2048);
      gload16(Bg + (size_t)(i * 32) * K + kt, Bsl + i * 2048);
    }
    __syncthreads();
#pragma unroll
    for (int kk = 0; kk < 2; ++kk) {
      bf16x8 af[4], bfr[4];
#pragma unroll
      for (int m = 0; m < 4; ++m)
        af[m] = *(const bf16x8*)(As + (wm * 64 + m * 16 + (lane & 15)) * 64 + kk * 32 + (lane >> 4) * 8);
#pragma unroll
      for (int n = 0; n < 4; ++n)
        bfr[n] = *(const bf16x8*)(Bs + (wn * 64 + n * 16 + (lane & 15)) * 64 + kk * 32 + (lane >> 4) * 8);
#pragma unroll
      for (int m = 0; m < 4; ++m)
#pragma unroll
        for (int n = 0; n < 4; ++n)
          acc[m][n] = __builtin_amdgcn_mfma_f32_16x16x32_bf16(af[m], bfr[n], acc[m][n], 0, 0, 0);
    }
    __syncthreads();
  }

  const int r0 = (lane >> 4) * 4;
  const int c0 = lane & 15;
#pragma unroll
  for (int m = 0; m < 4; ++m) {
#pragma unroll
    for (int n = 0; n < 4; ++n) {
      const int col = n0 + wn * 64 + n * 16 + c0;
      const float bv = bias[col];
#pragma unroll
      for (int r = 0; r < 4; ++r) {
        const int row = m0 + wm * 64 + m * 16 + r0 + r;
        const float v = acc[m][n][r] + bv;
        if (OUT_MODE == 0) {
          ((u16*)Cp)[(size_t)row * ldc + col] = f2bf(v);
        } else if (OUT_MODE == 2) {
          ((float*)Cp)[(size_t)row * ldc + col] = v;
        }
      }
    }
  }
}

// ---------------- 256x256 8-phase pipelined GEMM (K=1024, BK=64) ----------------
// 8 waves (2M x 4N), per-wave 128x64. 16 K-tiles, 4 phases/tile (kk-half x m-half).
// 2 LDS dbuf x 64KB. Row-XOR chunk swizzle (T2) via pre-swizzled global source.
// Counted vmcnt(2) only at P1/P4 phase ends, before the barrier (T3/T4).
// setprio around MFMA (T5). Bijective XCD grid swizzle (T1).
// OUT_MODE: 0 bf16 row-major, 1 qkv-head scatter, 2 f32 row-major, 3 bf16+rope
// SCALEQ: scale cols [0,1024) by 0.125 in head-scatter mode (softmax scale fold)
template <int OUT_MODE, int ACOLB, int SCALEQ = 0>
__global__ __launch_bounds__(512, 2) void k_gemm256(
    const u16* __restrict__ A, int lda, const u16* __restrict__ Bw,
    const float* __restrict__ bias, void* __restrict__ Cp, int ldc,
    size_t thirdStride, const float* __restrict__ tab, int Nt) {
  __shared__ u16 lds[2 * 32768];  // 2 x (A[256][64] + B[256][64]) bf16 = 128KB

  const int tid = threadIdx.x, lane = tid & 63, wave = tid >> 6;
  const int wm = wave >> 2, wn = wave & 3;
  const int c0 = lane & 15, hi = lane >> 4;

  // bijective XCD swizzle (m204), n-tile inner
  const int nwg = gridDim.x;
  const int qq = nwg >> 3, rr_ = nwg & 7;
  const int xcd = blockIdx.x & 7, sub = blockIdx.x >> 3;
  const int seq = (xcd < rr_ ? xcd * (qq + 1) : rr_ * (qq + 1) + (xcd - rr_) * qq) + sub;
  const int mt = seq / Nt, nt = seq - mt * Nt;
  const int m0 = mt * 256, n0 = nt * 256;
  const int aoff = ACOLB ? (n0 & ~1023) : 0;

  // ---- staging geometry: 8 load-rounds/tile (A: L0-3 rows 64L.., B: L4-7) ----
  // thread covers row rl=tid>>3 of the round, phys chunk pc=tid&7; global chunk
  // gc = pc ^ (rl&7) (inverse swizzle on SOURCE; LDS dest stays linear).
  const int rl = tid >> 3, pc = tid & 7;
  const int gc = pc ^ (rl & 7);
  const u16* aS = A + (size_t)(m0 + rl) * lda + aoff + gc * 8;
  const u16* bS = Bw + (size_t)(n0 + rl) * 1024 + gc * 8;
  const uint32_t ldsW = wave * 512;  // u16: wave-uniform base inside round region

  auto stageR = [&](int tt, int L) {
    const int bb = (tt & 1) * 32768;
    const u16* src = (L < 4) ? (aS + (size_t)(L * 64) * lda + tt * 64)
                             : (bS + (size_t)((L - 4) * 64) * 1024 + tt * 64);
    gload16(src, (u16*)lds + bb + L * 4096 + ldsW);
  };

  // ---- fragment read offsets (u16), swizzled: phys chunk = (kk*4+hi)^(row&7) ----
  int aofr[2][8], bofr[2][4];
#pragma unroll
  for (int kk = 0; kk < 2; ++kk) {
#pragma unroll
    for (int m = 0; m < 8; ++m)
      aofr[kk][m] = (wm * 128 + m * 16 + c0) * 64 + (((kk * 4 + hi) ^ (c0 & 7)) * 8);
#pragma unroll
    for (int n = 0; n < 4; ++n)
      bofr[kk][n] = 16384 + (wn * 64 + n * 16 + c0) * 64 + (((kk * 4 + hi) ^ (c0 & 7)) * 8);
  }

  // ---- prologue: stage tile 0 in phase-issue order; counted wait ----
  stageR(0, 0); stageR(0, 2); stageR(0, 4); stageR(0, 5);
  stageR(0, 6); stageR(0, 7); stageR(0, 1); stageR(0, 3);
  asm volatile("s_waitcnt vmcnt(2)" ::: "memory");
  __builtin_amdgcn_s_barrier();

  f32x4 acc[8][4] = {};
  bf16x8 bfr[4], af[4];

#define MFMA16(MB)                                                              \
  _Pragma("unroll") for (int m = 0; m < 4; ++m)                                 \
  _Pragma("unroll") for (int n = 0; n < 4; ++n)                                 \
      acc[(MB) + m][n] =                                                        \
          __builtin_amdgcn_mfma_f32_16x16x32_bf16(af[m], bfr[n], acc[(MB) + m][n], 0, 0, 0);

#define PH_MID()                                                 \
  __builtin_amdgcn_s_barrier();                                  \
  asm volatile("s_waitcnt lgkmcnt(0)" ::: "memory");             \
  __builtin_amdgcn_sched_barrier(0);                             \
  __builtin_amdgcn_s_setprio(1);

#define PH_END()                                                 \
  __builtin_amdgcn_s_setprio(0);                                 \
  __builtin_amdgcn_sched_barrier(0);

  for (int t = 0; t < 16; ++t) {
    const u16* buf = lds + (t & 1) * 32768;
    const bool pf = (t < 15);

    // ---- P1: kk0, m-half0 ----
#pragma unroll
    for (int n = 0; n < 4; ++n) bfr[n] = *(const bf16x8*)(buf + bofr[0][n]);
#pragma unroll
    for (int m = 0; m < 4; ++m) af[m] = *(const bf16x8*)(buf + aofr[0][m]);
    if (pf) { stageR(t + 1, 0); stageR(t + 1, 2); }
    PH_MID();
    MFMA16(0);
    PH_END();
    if (pf) asm volatile("s_waitcnt vmcnt(2)" ::: "memory");   // drain this tile's L1,L3
    else    asm volatile("s_waitcnt vmcnt(0)" ::: "memory");
    __builtin_amdgcn_s_barrier();

    // ---- P2: kk0, m-half1 ----
#pragma unroll
    for (int m = 0; m < 4; ++m) af[m] = *(const bf16x8*)(buf + aofr[0][4 + m]);
    if (pf) { stageR(t + 1, 4); stageR(t + 1, 5); }
    PH_MID();
    MFMA16(4);
    PH_END();
    __builtin_amdgcn_s_barrier();

    // ---- P3: kk1, m-half0 ----
#pragma unroll
    for (int n = 0; n < 4; ++n) bfr[n] = *(const bf16x8*)(buf + bofr[1][n]);
#pragma unroll
    for (int m = 0; m < 4; ++m) af[m] = *(const bf16x8*)(buf + aofr[1][m]);
    if (pf) { stageR(t + 1, 6); stageR(t + 1, 7); }
    PH_MID();
    MFMA16(0);
    PH_END();
    __builtin_amdgcn_s_barrier();

    // ---- P4: kk1, m-half1 ----
#pragma unroll
    for (int m = 0; m < 4; ++m) af[m] = *(const bf16x8*)(buf + aofr[1][4 + m]);
    if (pf) { stageR(t + 1, 1); stageR(t + 1, 3); }
    PH_MID();
    MFMA16(4);
    PH_END();
    if (pf) asm volatile("s_waitcnt vmcnt(2)" ::: "memory");   // next tile's first 6 landed
    __builtin_amdgcn_s_barrier();
  }
#undef MFMA16
#undef PH_MID
#undef PH_END

  // ---- epilogue ----
  const int r0 = (lane >> 4) * 4;
#pragma unroll
  for (int m = 0; m < 8; ++m) {
#pragma unroll
    for (int n = 0; n < 4; ++n) {
      const int col = n0 + wn * 64 + n * 16 + c0;
      const float bv = bias[col];
      if (OUT_MODE == 3) {
        const int pairI = (col & 1023) >> 1;
        const float sgn = (col & 1) ? 1.f : -1.f;
#pragma unroll
        for (int r = 0; r < 4; ++r) {
          const int row = m0 + wm * 128 + m * 16 + r0 + r;
          const float v = acc[m][n][r] + bv;
          const float p = __shfl_xor(v, 1);
          const float2 cs = ((const float2*)tab)[(row >> 8) * 512 + pairI];
          ((u16*)Cp)[(size_t)row * ldc + col] = f2bf(v * cs.x + sgn * p * cs.y);
        }
      } else {
#pragma unroll
        for (int r = 0; r < 4; ++r) {
          const int row = m0 + wm * 128 + m * 16 + r0 + r;
          const float v = acc[m][n][r] + bv;
          if (OUT_MODE == 0) {
            ((u16*)Cp)[(size_t)row * ldc + col] = f2bf(v);
          } else if (OUT_MODE == 2) {
            ((float*)Cp)[(size_t)row * ldc + col] = v;
          } else {
            const int which = col >> 10, c = col & 1023;
            const int h = c >> 6, d = c & 63;
            const int s = row >> 8, b = row & 255;
            const float sc = (SCALEQ && which == 0) ? 0.125f : 1.0f;
            ((u16*)Cp)[(size_t)which * thirdStride +
                       (((size_t)(b * NH + h) * S_LEN + s) * HDIM + d)] = f2bf(v * sc);
          }
        }
      }
    }
  }
}

// ---------------- attention: one block (512 thr, 8 waves) per (b,h) ----------------
__global__ __launch_bounds__(512, 6) void k_attn(const u16* __restrict__ qkv2,
                                                 const float* __restrict__ maskP,
                                                 u16* __restrict__ O1) {
  __shared__ u16 Vt[64 * 128];     // Vt[d][s ^ ((d&7)<<3)]   16KB
  __shared__ u16 Pb[128 * 128];    // Pb[q][s ^ ((q&7)<<3)]   32KB
  __shared__ float redM[4][128];
  __shared__ float redS[4][128];

  const size_t TS = (size_t)MROWS * W_DIM;
  const int bh = blockIdx.x, b = bh >> 4, h = bh & 15;
  const int tid = threadIdx.x, lane = tid & 63, wave = tid >> 6;
  const int wm = wave >> 2;
  const int wn = wave & 3;
  const int c0 = lane & 15, hi = lane >> 4;

  const u16* Qg = qkv2 + (size_t)bh * (S_LEN * HDIM);
  const u16* Kg = Qg + TS;
  const u16* Vg = Qg + 2 * TS;

  for (int idx = tid; idx < 1024; idx += 512) {
    const int s = idx >> 3, c = (idx & 7) * 8;
    uint4 vv = make_uint4(0, 0, 0, 0);
    if (s < S_LEN) vv = *(const uint4*)(Vg + (size_t)s * HDIM + c);
    u16 tmp[8];
    *(uint4*)tmp = vv;
#pragma unroll
    for (int j = 0; j < 8; ++j)
      Vt[(c + j) * 128 + (s ^ (j << 3))] = tmp[j];
  }

  f32x4 acc[4][2] = {};
#pragma unroll
  for (int kk = 0; kk < 2; ++kk) {
    bf16x8 af[4], bfr[2];
#pragma unroll
    for (int m = 0; m < 4; ++m)
      af[m] = *(const bf16x8*)(Qg + (size_t)(wm * 64 + m * 16 + c0) * HDIM + kk * 32 + hi * 8);
#pragma unroll
    for (int n = 0; n < 2; ++n)
      bfr[n] = *(const bf16x8*)(Kg + (size_t)(wn * 32 + n * 16 + c0) * HDIM + kk * 32 + hi * 8);
#pragma unroll
    for (int m = 0; m < 4; ++m)
#pragma unroll
      for (int n = 0; n < 2; ++n)
        acc[m][n] = __builtin_amdgcn_mfma_f32_16x16x32_bf16(af[m], bfr[n], acc[m][n], 0, 0, 0);
  }

#pragma unroll
  for (int m = 0; m < 4; ++m) {
    float mxm[4];
#pragma unroll
    for (int r = 0; r < 4; ++r) {
      const int row = wm * 64 + m * 16 + hi * 4 + r;
#pragma unroll
      for (int n = 0; n < 2; ++n)
        acc[m][n][r] += maskP[row * 128 + wn * 32 + n * 16 + c0];
      mxm[r] = fmaxf(acc[m][0][r], acc[m][1][r]);
    }
#pragma unroll
    for (int d = 1; d < 16; d <<= 1)
#pragma unroll
      for (int r = 0; r < 4; ++r)
        mxm[r] = fmaxf(mxm[r], __shfl_xor(mxm[r], d));
    if (c0 == 0) {
#pragma unroll
      for (int r = 0; r < 4; ++r)
        redM[wn][wm * 64 + m * 16 + hi * 4 + r] = mxm[r];
    }
  }
  __syncthreads();

#pragma unroll
  for (int m = 0; m < 4; ++m) {
    float psm[4];
#pragma unroll
    for (int r = 0; r < 4; ++r) {
      const int row = wm * 64 + m * 16 + hi * 4 + r;
      const float rm = fmaxf(fmaxf(redM[0][row], redM[1][row]),
                             fmaxf(redM[2][row], redM[3][row]));
      float p = 0.f;
#pragma unroll
      for (int n = 0; n < 2; ++n) {
        const float e = __expf(acc[m][n][r] - rm);
        p += e;
        const int col = wn * 32 + n * 16 + c0;
        Pb[row * 128 + (col ^ ((row & 7) << 3))] = f2bf(e);
      }
      psm[r] = p;
    }
#pragma unroll
    for (int d = 1; d < 16; d <<= 1)
#pragma unroll
      for (int r = 0; r < 4; ++r)
        psm[r] += __shfl_xor(psm[r], d);
    if (c0 == 0) {
#pragma unroll
      for (int r = 0; r < 4; ++r)
        redS[wn][wm * 64 + m * 16 + hi * 4 + r] = psm[r];
    }
  }
  __syncthreads();

  f32x4 o[4] = {};
#pragma unroll
  for (int kk = 0; kk < 4; ++kk) {
    bf16x8 pa[4], vb;
#pragma unroll
    for (int m = 0; m < 4; ++m) {
      const int row = wm * 64 + m * 16 + c0;
      pa[m] = *(const bf16x8*)(Pb + row * 128 + ((kk * 32 + hi * 8) ^ ((row & 7) << 3)));
    }
    {
      const int d = wn * 16 + c0;
      vb = *(const bf16x8*)(Vt + d * 128 + ((kk * 32 + hi * 8) ^ ((d & 7) << 3)));
    }
#pragma unroll
    for (int m = 0; m < 4; ++m)
      o[m] = __builtin_amdgcn_mfma_f32_16x16x32_bf16(pa[m], vb, o[m], 0, 0, 0);
  }

#pragma unroll
  for (int m = 0; m < 4; ++m)
#pragma unroll
    for (int r = 0; r < 4; ++r) {
      const int row = wm * 64 + m * 16 + hi * 4 + r;
      if (row < S_LEN) {
        const float iv = 1.0f / (redS[0][row] + redS[1][row] + redS[2][row] + redS[3][row]);
        const int d = wn * 16 + c0;
        O1[((size_t)row * B_DIM + b) * W_DIM + h * HDIM + d] = f2bf(o[m][r] * iv);
      }
    }
}

// ---------------- launcher ----------------
extern "C" void kernel_launch(void* const* d_in, const int* in_sizes, int n_in,
                              void* d_out, int out_size, void* d_ws, size_t ws_size,
                              hipStream_t stream) {
  (void)in_sizes; (void)n_in; (void)out_size; (void)ws_size;
  const float* tensor    = (const float*)d_in[0];
  const float* mask      = (const float*)d_in[1];
  const float* q_w       = (const float*)d_in[2];
  const float* q_b       = (const float*)d_in[3];
  const float* k_w       = (const float*)d_in[4];
  const float* k_b       = (const float*)d_in[5];
  const float* v_w       = (const float*)d_in[6];
  const float* v_b       = (const float*)d_in[7];
  const float* in_proj_w = (const float*)d_in[8];
  const float* in_proj_b = (const float*)d_in[9];
  const float* mha_w     = (const float*)d_in[10];
  const float* mha_b     = (const float*)d_in[11];
  const float* out_w     = (const float*)d_in[12];
  const float* out_b     = (const float*)d_in[13];

  char* ws = (char*)d_ws;
  size_t off = 0;
  auto alloc = [&](size_t bytes) {
    char* p = ws + off;
    off += (bytes + 255) & ~(size_t)255;
    return p;
  };

  const size_t TS = (size_t)MROWS * W_DIM;

  float* tab = (float*)alloc((size_t)S_LEN * 512 * 2 * sizeof(float));
  float* maskP = (float*)alloc((size_t)128 * 128 * sizeof(float));
  u16* Xbf   = (u16*)alloc(TS * 2);                          // reused as O1
  u16* qkv1  = (u16*)alloc((size_t)MROWS * 2048 * 2);        // q,k after GEMM1+rope
  u16* qkv2  = (u16*)alloc(TS * 3 * 2);                      // q,k,v head layout
  u16* WC1   = (u16*)alloc((size_t)2048 * 1024 * 2);         // [q_w;k_w] bf16
  u16* W2    = (u16*)alloc((size_t)3072 * 1024 * 2);         // in_proj bf16
  u16* WvT   = (u16*)alloc((size_t)1024 * 1024 * 2);
  u16* WmT   = (u16*)alloc((size_t)1024 * 1024 * 2);
  u16* WO    = (u16*)alloc((size_t)1024 * 1024 * 2);
  u16* WVf   = (u16*)alloc((size_t)1024 * 1024 * 2);         // Wv2 @ Wv
  u16* WFf   = (u16*)alloc((size_t)1024 * 1024 * 2);         // Wo @ Wm
  float* bc1 = (float*)alloc(2048 * sizeof(float));
  float* bvf = (float*)alloc(1024 * sizeof(float));
  float* bff = (float*)alloc(1024 * sizeof(float));
  float* zb  = (float*)alloc(1024 * sizeof(float));
  u16* O1 = Xbf;  // X dead after GEMM_v

  // ---- prep / converts ----
  k_rope_tab<<<dim3((S_LEN * 512 + 255) / 256), 256, 0, stream>>>(tab);
  k_maskpad<<<dim3(64), 256, 0, stream>>>(mask, maskP);
  k_cvt<<<dim3(MROWS * W_DIM / 4 / 256), 256, 0, stream>>>(tensor, Xbf, MROWS * W_DIM / 4);
  k_cvt<<<dim3(1024), 256, 0, stream>>>(q_w, WC1, 262144);
  k_cvt<<<dim3(1024), 256, 0, stream>>>(k_w, WC1 + 1048576, 262144);
  k_cvt<<<dim3(3072), 256, 0, stream>>>(in_proj_w, W2, 786432);
  k_cvt<<<dim3(1024), 256, 0, stream>>>(out_w, WO, 262144);
  k_cvt_t<<<dim3(32, 32), dim3(32, 8), 0, stream>>>(v_w, WvT);
  k_cvt_t<<<dim3(32, 32), dim3(32, 8), 0, stream>>>(mha_w, WmT);
  k_bias2<<<dim3(8), 256, 0, stream>>>(q_b, k_b, bc1);
  k_zero<<<dim3(4), 256, 0, stream>>>(zb, 1024);
  k_biasfold<<<dim3(256), 256, 0, stream>>>(in_proj_w + (size_t)2048 * 1024, v_b,
                                            in_proj_b + 2048, bvf);
  k_biasfold<<<dim3(256), 256, 0, stream>>>(out_w, mha_b, out_b, bff);

  // ---- weight folds (1024^3 bf16 GEMMs, small kernel) ----
  k_gemm<0><<<dim3(8, 8), 256, 0, stream>>>(
      W2 + (size_t)2048 * 1024, 1024, WvT, zb, WVf, 1024, 1024);
  k_gemm<0><<<dim3(8, 8), 256, 0, stream>>>(
      WO, 1024, WmT, zb, WFf, 1024, 1024);

  // ---- GEMM1 + fused rope: X @ [q_w;k_w]^T + bias -> qkv1 (24832 x 2048) ----
  k_gemm256<3, 0><<<dim3(97 * 8), 512, 0, stream>>>(
      Xbf, W_DIM, WC1, bc1, qkv1, 2048, 0, tab, 8);

  // ---- v path (folded): X @ WVf^T + bvf -> v heads ----
  k_gemm256<1, 0><<<dim3(97 * 4), 512, 0, stream>>>(
      Xbf, W_DIM, WVf, bvf, qkv2 + 2 * TS, 0, TS, nullptr, 4);

  // ---- GEMM2 (block-diagonal): qkv1 @ [Wq2;Wk2]^T + b -> q,k heads (q scaled 1/8) ----
  k_gemm256<1, 1, 1><<<dim3(97 * 8), 512, 0, stream>>>(
      qkv1, 2048, W2, in_proj_b, qkv2, 0, TS, nullptr, 8);

  // ---- attention ----
  k_attn<<<dim3(B_DIM * NH), 512, 0, stream>>>(qkv2, maskP, O1);

  // ---- output (folded): O1 @ WFf^T + bff -> d_out (fp32) ----
  k_gemm256<2, 0><<<dim3(97 * 4), 512, 0, stream>>>(
      O1, W_DIM, WFf, bff, d_out, W_DIM, 0, nullptr, 4);
}

// Round 7
// 608.186 us; speedup vs baseline: 1.8080x; 1.0108x over previous
//
#include <hip/hip_runtime.h>
#include <cstdint>
#include <cstddef>

#define S_LEN 97
#define B_DIM 256
#define W_DIM 1024
#define NH    16
#define HDIM  64
#define MROWS (S_LEN * B_DIM)   // 24832 = 97*256

typedef unsigned short u16;
typedef __bf16 bf16x8 __attribute__((ext_vector_type(8)));
typedef float  f32x4  __attribute__((ext_vector_type(4)));

__device__ __forceinline__ u16 f2bf(float f) {
  union { float f; uint32_t u; } v; v.f = f;
  uint32_t u = v.u;
  return (u16)((u + 0x7FFFu + ((u >> 16) & 1u)) >> 16);  // RNE
}
__device__ __forceinline__ float bf2f(u16 h) {
  union { uint32_t u; float f; } v; v.u = ((uint32_t)h) << 16;
  return v.f;
}

// async global->LDS, 16B per lane. LDS dest must be wave-uniform base; HW adds lane*16.
__device__ __forceinline__ void gload16(const void* g, void* lds) {
  __builtin_amdgcn_global_load_lds(
      (const __attribute__((address_space(1))) void*)(uintptr_t)g,
      (__attribute__((address_space(3))) void*)(uint32_t)(uintptr_t)lds,
      16, 0, 0);
}

// ---------------- prep kernels ----------------
__global__ void k_cvt(const float* __restrict__ s, u16* __restrict__ d, int n4) {
  int i = blockIdx.x * blockDim.x + threadIdx.x;
  if (i >= n4) return;
  float4 v = ((const float4*)s)[i];
  uint2 pk;
  pk.x = (uint32_t)f2bf(v.x) | ((uint32_t)f2bf(v.y) << 16);
  pk.y = (uint32_t)f2bf(v.z) | ((uint32_t)f2bf(v.w) << 16);
  ((uint2*)d)[i] = pk;
}

// dst = src^T (1024x1024), fp32 -> bf16
__global__ void k_cvt_t(const float* __restrict__ src, u16* __restrict__ dst) {
  __shared__ float t[32][33];
  const int bx = blockIdx.x * 32, by = blockIdx.y * 32;
  const int tx = threadIdx.x, ty = threadIdx.y;  // 32 x 8
  for (int yy = ty; yy < 32; yy += 8)
    t[yy][tx] = src[(size_t)(by + yy) * 1024 + bx + tx];
  __syncthreads();
  for (int yy = ty; yy < 32; yy += 8)
    dst[(size_t)(bx + yy) * 1024 + by + tx] = f2bf(t[tx][yy]);
}

__global__ void k_bias2(const float* a, const float* b, float* dst) {
  int i = blockIdx.x * blockDim.x + threadIdx.x;
  if (i >= 2 * W_DIM) return;
  dst[i] = (i < W_DIM) ? a[i] : b[i - W_DIM];
}

__global__ void k_zero(float* dst, int n) {
  int i = blockIdx.x * blockDim.x + threadIdx.x;
  if (i < n) dst[i] = 0.f;
}

// padded mask: maskP[r][c] = mask[r][c] (r,c<97), -1e30 for c>=97, 0 for r>=97
__global__ void k_maskpad(const float* __restrict__ mask, float* __restrict__ mp) {
  int i = blockIdx.x * blockDim.x + threadIdx.x;  // 0..16383
  int r = i >> 7, c = i & 127;
  float v;
  if (c >= S_LEN) v = -1e30f;
  else if (r < S_LEN) v = mask[r * S_LEN + c];
  else v = 0.f;
  mp[i] = v;
}

// out[row] = dot(M[row,:], v) + b2[row]   (M: 1024x1024 fp32)
__global__ void k_biasfold(const float* __restrict__ M, const float* __restrict__ v,
                           const float* __restrict__ b2, float* __restrict__ out) {
  const int lane = threadIdx.x & 63, wave = threadIdx.x >> 6;
  const int row = blockIdx.x * 4 + wave;
  float s = 0.f;
  for (int k = lane; k < 1024; k += 64) s += M[(size_t)row * 1024 + k] * v[k];
#pragma unroll
  for (int d = 32; d; d >>= 1) s += __shfl_xor(s, d);
  if (lane == 0) out[row] = s + b2[row];
}

__global__ void k_rope_tab(float* __restrict__ tab) {
  int idx = blockIdx.x * blockDim.x + threadIdx.x;
  if (idx >= S_LEN * 512) return;
  int s = idx / 512, i = idx % 512;
  float freq = expf(-(float)i * (9.210340371976184f / 512.0f));
  float ang = (float)s * freq;
  float sv, cv;
  sincosf(ang, &sv, &cv);
  tab[idx * 2 + 0] = cv;
  tab[idx * 2 + 1] = sv;
}

// ---------------- small 128x128 GEMM (weight folds only) ----------------
template <int OUT_MODE>
__global__ __launch_bounds__(256) void k_gemm(
    const u16* __restrict__ A, int lda, const u16* __restrict__ Bw,
    const float* __restrict__ bias, void* __restrict__ Cp, int ldc, int K) {
  __shared__ u16 As[128 * 64];
  __shared__ u16 Bs[128 * 64];

  const int tid = threadIdx.x, lane = tid & 63, wave = tid >> 6;
  const int wm = wave >> 1, wn = wave & 1;
  const int m0 = blockIdx.y * 128;
  const int n0 = blockIdx.x * 128;

  f32x4 acc[4][4] = {};

  const int lrow = lane >> 3;
  const int lcol = (lane & 7) * 8;
  const u16* Ag = A + (size_t)(m0 + wave * 8 + lrow) * lda + lcol;
  const u16* Bg = Bw + (size_t)(n0 + wave * 8 + lrow) * K + lcol;
  u16* Asl = As + wave * 8 * 64;
  u16* Bsl = Bs + wave * 8 * 64;

  for (int kt = 0; kt < K; kt += 64) {
#pragma unroll
    for (int i = 0; i < 4; ++i) {
      gload16(Ag + (size_t)(i * 32) * lda + kt, Asl + i * 2048);
      gload16(Bg + (size_t)(i * 32) * K + kt, Bsl + i * 2048);
    }
    __syncthreads();
#pragma unroll
    for (int kk = 0; kk < 2; ++kk) {
      bf16x8 af[4], bfr[4];
#pragma unroll
      for (int m = 0; m < 4; ++m)
        af[m] = *(const bf16x8*)(As + (wm * 64 + m * 16 + (lane & 15)) * 64 + kk * 32 + (lane >> 4) * 8);
#pragma unroll
      for (int n = 0; n < 4; ++n)
        bfr[n] = *(const bf16x8*)(Bs + (wn * 64 + n * 16 + (lane & 15)) * 64 + kk * 32 + (lane >> 4) * 8);
#pragma unroll
      for (int m = 0; m < 4; ++m)
#pragma unroll
        for (int n = 0; n < 4; ++n)
          acc[m][n] = __builtin_amdgcn_mfma_f32_16x16x32_bf16(af[m], bfr[n], acc[m][n], 0, 0, 0);
    }
    __syncthreads();
  }

  const int r0 = (lane >> 4) * 4;
  const int c0 = lane & 15;
#pragma unroll
  for (int m = 0; m < 4; ++m) {
#pragma unroll
    for (int n = 0; n < 4; ++n) {
      const int col = n0 + wn * 64 + n * 16 + c0;
      const float bv = bias[col];
#pragma unroll
      for (int r = 0; r < 4; ++r) {
        const int row = m0 + wm * 64 + m * 16 + r0 + r;
        const float v = acc[m][n][r] + bv;
        if (OUT_MODE == 0) {
          ((u16*)Cp)[(size_t)row * ldc + col] = f2bf(v);
        } else if (OUT_MODE == 2) {
          ((float*)Cp)[(size_t)row * ldc + col] = v;
        }
      }
    }
  }
}

// ---------------- 256x256 register-pipelined GEMM (K=1024, BK=64) ----------------
// 8 waves (2M x 4N), per-wave 128x64. 16 K-tiles, 4 MFMA clusters/tile.
// Register double-buffered fragments: ds_reads for cluster p+1 issued before
// MFMA(p); compiler inserts counted lgkmcnt. ONE barrier per tile (boundary):
// MFMA(p3) consumes all tile reads -> vmcnt(0) (t+1 stages, issued >=1 phase
// earlier) -> s_barrier -> read p0 frags from buf^1. Stages spread 3/3/2 over
// p0-p2. Row-XOR chunk swizzle (T2) via pre-swizzled global source.
// setprio around MFMA (T5). Bijective XCD grid swizzle (T1).
// OUT_MODE: 0 bf16 row-major, 1 qkv-head scatter, 2 f32 row-major, 3 bf16+rope
// SCALEQ: scale cols [0,1024) by 0.125 in head-scatter mode (softmax scale fold)
template <int OUT_MODE, int ACOLB, int SCALEQ = 0>
__global__ __launch_bounds__(512, 2) void k_gemm256(
    const u16* __restrict__ A, int lda, const u16* __restrict__ Bw,
    const float* __restrict__ bias, void* __restrict__ Cp, int ldc,
    size_t thirdStride, const float* __restrict__ tab, int Nt) {
  __shared__ u16 lds[2 * 32768];  // 2 x (A[256][64] + B[256][64]) bf16 = 128KB

  const int tid = threadIdx.x, lane = tid & 63, wave = tid >> 6;
  const int wm = wave >> 2, wn = wave & 3;
  const int c0 = lane & 15, hi = lane >> 4;

  // bijective XCD swizzle (m204), n-tile inner
  const int nwg = gridDim.x;
  const int qq = nwg >> 3, rr_ = nwg & 7;
  const int xcd = blockIdx.x & 7, sub = blockIdx.x >> 3;
  const int seq = (xcd < rr_ ? xcd * (qq + 1) : rr_ * (qq + 1) + (xcd - rr_) * qq) + sub;
  const int mt = seq / Nt, nt = seq - mt * Nt;
  const int m0 = mt * 256, n0 = nt * 256;
  const int aoff = ACOLB ? (n0 & ~1023) : 0;

  // ---- staging geometry: 8 load-rounds/tile (A: L0-3, B: L4-7) ----
  // thread covers row rl=tid>>3, phys chunk pc=tid&7; global chunk gc=pc^(rl&7)
  // (inverse swizzle on SOURCE; LDS dest stays linear).
  const int rl = tid >> 3, pc = tid & 7;
  const int gc = pc ^ (rl & 7);
  const u16* aS = A + (size_t)(m0 + rl) * lda + aoff + gc * 8;
  const u16* bS = Bw + (size_t)(n0 + rl) * 1024 + gc * 8;
  const uint32_t ldsW = wave * 512;  // u16: wave-uniform base inside round region

  auto stageR = [&](int tt, int L) {
    const int bb = (tt & 1) * 32768;
    const u16* src = (L < 4) ? (aS + (size_t)(L * 64) * lda + tt * 64)
                             : (bS + (size_t)((L - 4) * 64) * 1024 + tt * 64);
    gload16(src, (u16*)lds + bb + L * 4096 + ldsW);
  };

  // ---- fragment read offsets (u16), swizzled: phys chunk = (kk*4+hi)^(row&7) ----
  int aofr[2][8], bofr[2][4];
#pragma unroll
  for (int kk = 0; kk < 2; ++kk) {
#pragma unroll
    for (int m = 0; m < 8; ++m)
      aofr[kk][m] = (wm * 128 + m * 16 + c0) * 64 + (((kk * 4 + hi) ^ (c0 & 7)) * 8);
#pragma unroll
    for (int n = 0; n < 4; ++n)
      bofr[kk][n] = 16384 + (wn * 64 + n * 16 + c0) * 64 + (((kk * 4 + hi) ^ (c0 & 7)) * 8);
  }

  // ---- prologue: stage tile 0, wait, read p0 fragments ----
  stageR(0, 0); stageR(0, 1); stageR(0, 2); stageR(0, 3);
  stageR(0, 4); stageR(0, 5); stageR(0, 6); stageR(0, 7);
  asm volatile("s_waitcnt vmcnt(0)" ::: "memory");
  __builtin_amdgcn_s_barrier();

  f32x4 acc[8][4] = {};
  bf16x8 afP[4], afN[4], bfrC[4], bfrN[4];

  {
    const u16* buf = lds;
#pragma unroll
    for (int n = 0; n < 4; ++n) bfrC[n] = *(const bf16x8*)(buf + bofr[0][n]);
#pragma unroll
    for (int m = 0; m < 4; ++m) afP[m] = *(const bf16x8*)(buf + aofr[0][m]);
  }

#define MFMA16(MB, AF, BF)                                                      \
  _Pragma("unroll") for (int m = 0; m < 4; ++m)                                 \
  _Pragma("unroll") for (int n = 0; n < 4; ++n)                                 \
      acc[(MB) + m][n] =                                                        \
          __builtin_amdgcn_mfma_f32_16x16x32_bf16(AF[m], BF[n], acc[(MB) + m][n], 0, 0, 0);

  for (int t = 0; t < 16; ++t) {
    const u16* buf = lds + (t & 1) * 32768;
    const u16* nbuf = lds + ((t + 1) & 1) * 32768;
    const bool pf = (t < 15);

    // ---- p0: MFMA(kk0,mh0); issue af(kk0,mh1); stage 3 ----
#pragma unroll
    for (int m = 0; m < 4; ++m) afN[m] = *(const bf16x8*)(buf + aofr[0][4 + m]);
    if (pf) { stageR(t + 1, 0); stageR(t + 1, 2); stageR(t + 1, 4); }
    __builtin_amdgcn_s_setprio(1);
    MFMA16(0, afP, bfrC);
    __builtin_amdgcn_s_setprio(0);

    // ---- p1: MFMA(kk0,mh1); issue bfr(kk1), af(kk1,mh0); stage 3 ----
#pragma unroll
    for (int n = 0; n < 4; ++n) bfrN[n] = *(const bf16x8*)(buf + bofr[1][n]);
#pragma unroll
    for (int m = 0; m < 4; ++m) afP[m] = *(const bf16x8*)(buf + aofr[1][m]);
    if (pf) { stageR(t + 1, 5); stageR(t + 1, 6); stageR(t + 1, 7); }
    __builtin_amdgcn_s_setprio(1);
    MFMA16(4, afN, bfrC);
    __builtin_amdgcn_s_setprio(0);

    // ---- p2: MFMA(kk1,mh0); issue af(kk1,mh1); stage 2 ----
#pragma unroll
    for (int m = 0; m < 4; ++m) afN[m] = *(const bf16x8*)(buf + aofr[1][4 + m]);
    if (pf) { stageR(t + 1, 1); stageR(t + 1, 3); }
    __builtin_amdgcn_s_setprio(1);
    MFMA16(0, afP, bfrN);
    __builtin_amdgcn_s_setprio(0);

    // ---- p3: MFMA(kk1,mh1) — consumes the last of this tile's reads ----
    __builtin_amdgcn_s_setprio(1);
    MFMA16(4, afN, bfrN);
    __builtin_amdgcn_s_setprio(0);

    // ---- tile boundary: all buf reads consumed; t+1 staged; swap ----
    if (pf) {
      asm volatile("s_waitcnt vmcnt(0)" ::: "memory");
      __builtin_amdgcn_s_barrier();
#pragma unroll
      for (int n = 0; n < 4; ++n) bfrC[n] = *(const bf16x8*)(nbuf + bofr[0][n]);
#pragma unroll
      for (int m = 0; m < 4; ++m) afP[m] = *(const bf16x8*)(nbuf + aofr[0][m]);
    }
  }
#undef MFMA16

  // ---- epilogue ----
  const int r0 = (lane >> 4) * 4;
#pragma unroll
  for (int m = 0; m < 8; ++m) {
#pragma unroll
    for (int n = 0; n < 4; ++n) {
      const int col = n0 + wn * 64 + n * 16 + c0;
      const float bv = bias[col];
      if (OUT_MODE == 3) {
        const int pairI = (col & 1023) >> 1;
        const float sgn = (col & 1) ? 1.f : -1.f;
#pragma unroll
        for (int r = 0; r < 4; ++r) {
          const int row = m0 + wm * 128 + m * 16 + r0 + r;
          const float v = acc[m][n][r] + bv;
          const float p = __shfl_xor(v, 1);
          const float2 cs = ((const float2*)tab)[(row >> 8) * 512 + pairI];
          ((u16*)Cp)[(size_t)row * ldc + col] = f2bf(v * cs.x + sgn * p * cs.y);
        }
      } else {
#pragma unroll
        for (int r = 0; r < 4; ++r) {
          const int row = m0 + wm * 128 + m * 16 + r0 + r;
          const float v = acc[m][n][r] + bv;
          if (OUT_MODE == 0) {
            ((u16*)Cp)[(size_t)row * ldc + col] = f2bf(v);
          } else if (OUT_MODE == 2) {
            ((float*)Cp)[(size_t)row * ldc + col] = v;
          } else {
            const int which = col >> 10, c = col & 1023;
            const int h = c >> 6, d = c & 63;
            const int s = row >> 8, b = row & 255;
            const float sc = (SCALEQ && which == 0) ? 0.125f : 1.0f;
            ((u16*)Cp)[(size_t)which * thirdStride +
                       (((size_t)(b * NH + h) * S_LEN + s) * HDIM + d)] = f2bf(v * sc);
          }
        }
      }
    }
  }
}

// ---------------- attention: one block (512 thr, 8 waves) per (b,h) ----------------
__global__ __launch_bounds__(512, 6) void k_attn(const u16* __restrict__ qkv2,
                                                 const float* __restrict__ maskP,
                                                 u16* __restrict__ O1) {
  __shared__ u16 Vt[64 * 128];     // Vt[d][s ^ ((d&7)<<3)]   16KB
  __shared__ u16 Pb[128 * 128];    // Pb[q][s ^ ((q&7)<<3)]   32KB
  __shared__ float redM[4][128];
  __shared__ float redS[4][128];

  const size_t TS = (size_t)MROWS * W_DIM;
  const int bh = blockIdx.x, b = bh >> 4, h = bh & 15;
  const int tid = threadIdx.x, lane = tid & 63, wave = tid >> 6;
  const int wm = wave >> 2;
  const int wn = wave & 3;
  const int c0 = lane & 15, hi = lane >> 4;

  const u16* Qg = qkv2 + (size_t)bh * (S_LEN * HDIM);
  const u16* Kg = Qg + TS;
  const u16* Vg = Qg + 2 * TS;

  for (int idx = tid; idx < 1024; idx += 512) {
    const int s = idx >> 3, c = (idx & 7) * 8;
    uint4 vv = make_uint4(0, 0, 0, 0);
    if (s < S_LEN) vv = *(const uint4*)(Vg + (size_t)s * HDIM + c);
    u16 tmp[8];
    *(uint4*)tmp = vv;
#pragma unroll
    for (int j = 0; j < 8; ++j)
      Vt[(c + j) * 128 + (s ^ (j << 3))] = tmp[j];
  }

  f32x4 acc[4][2] = {};
#pragma unroll
  for (int kk = 0; kk < 2; ++kk) {
    bf16x8 af[4], bfr[2];
#pragma unroll
    for (int m = 0; m < 4; ++m)
      af[m] = *(const bf16x8*)(Qg + (size_t)(wm * 64 + m * 16 + c0) * HDIM + kk * 32 + hi * 8);
#pragma unroll
    for (int n = 0; n < 2; ++n)
      bfr[n] = *(const bf16x8*)(Kg + (size_t)(wn * 32 + n * 16 + c0) * HDIM + kk * 32 + hi * 8);
#pragma unroll
    for (int m = 0; m < 4; ++m)
#pragma unroll
      for (int n = 0; n < 2; ++n)
        acc[m][n] = __builtin_amdgcn_mfma_f32_16x16x32_bf16(af[m], bfr[n], acc[m][n], 0, 0, 0);
  }

#pragma unroll
  for (int m = 0; m < 4; ++m) {
    float mxm[4];
#pragma unroll
    for (int r = 0; r < 4; ++r) {
      const int row = wm * 64 + m * 16 + hi * 4 + r;
#pragma unroll
      for (int n = 0; n < 2; ++n)
        acc[m][n][r] += maskP[row * 128 + wn * 32 + n * 16 + c0];
      mxm[r] = fmaxf(acc[m][0][r], acc[m][1][r]);
    }
#pragma unroll
    for (int d = 1; d < 16; d <<= 1)
#pragma unroll
      for (int r = 0; r < 4; ++r)
        mxm[r] = fmaxf(mxm[r], __shfl_xor(mxm[r], d));
    if (c0 == 0) {
#pragma unroll
      for (int r = 0; r < 4; ++r)
        redM[wn][wm * 64 + m * 16 + hi * 4 + r] = mxm[r];
    }
  }
  __syncthreads();

#pragma unroll
  for (int m = 0; m < 4; ++m) {
    float psm[4];
#pragma unroll
    for (int r = 0; r < 4; ++r) {
      const int row = wm * 64 + m * 16 + hi * 4 + r;
      const float rm = fmaxf(fmaxf(redM[0][row], redM[1][row]),
                             fmaxf(redM[2][row], redM[3][row]));
      float p = 0.f;
#pragma unroll
      for (int n = 0; n < 2; ++n) {
        const float e = __expf(acc[m][n][r] - rm);
        p += e;
        const int col = wn * 32 + n * 16 + c0;
        Pb[row * 128 + (col ^ ((row & 7) << 3))] = f2bf(e);
      }
      psm[r] = p;
    }
#pragma unroll
    for (int d = 1; d < 16; d <<= 1)
#pragma unroll
      for (int r = 0; r < 4; ++r)
        psm[r] += __shfl_xor(psm[r], d);
    if (c0 == 0) {
#pragma unroll
      for (int r = 0; r < 4; ++r)
        redS[wn][wm * 64 + m * 16 + hi * 4 + r] = psm[r];
    }
  }
  __syncthreads();

  f32x4 o[4] = {};
#pragma unroll
  for (int kk = 0; kk < 4; ++kk) {
    bf16x8 pa[4], vb;
#pragma unroll
    for (int m = 0; m < 4; ++m) {
      const int row = wm * 64 + m * 16 + c0;
      pa[m] = *(const bf16x8*)(Pb + row * 128 + ((kk * 32 + hi * 8) ^ ((row & 7) << 3)));
    }
    {
      const int d = wn * 16 + c0;
      vb = *(const bf16x8*)(Vt + d * 128 + ((kk * 32 + hi * 8) ^ ((d & 7) << 3)));
    }
#pragma unroll
    for (int m = 0; m < 4; ++m)
      o[m] = __builtin_amdgcn_mfma_f32_16x16x32_bf16(pa[m], vb, o[m], 0, 0, 0);
  }

#pragma unroll
  for (int m = 0; m < 4; ++m)
#pragma unroll
    for (int r = 0; r < 4; ++r) {
      const int row = wm * 64 + m * 16 + hi * 4 + r;
      if (row < S_LEN) {
        const float iv = 1.0f / (redS[0][row] + redS[1][row] + redS[2][row] + redS[3][row]);
        const int d = wn * 16 + c0;
        O1[((size_t)row * B_DIM + b) * W_DIM + h * HDIM + d] = f2bf(o[m][r] * iv);
      }
    }
}

// ---------------- launcher ----------------
extern "C" void kernel_launch(void* const* d_in, const int* in_sizes, int n_in,
                              void* d_out, int out_size, void* d_ws, size_t ws_size,
                              hipStream_t stream) {
  (void)in_sizes; (void)n_in; (void)out_size; (void)ws_size;
  const float* tensor    = (const float*)d_in[0];
  const float* mask      = (const float*)d_in[1];
  const float* q_w       = (const float*)d_in[2];
  const float* q_b       = (const float*)d_in[3];
  const float* k_w       = (const float*)d_in[4];
  const float* k_b       = (const float*)d_in[5];
  const float* v_w       = (const float*)d_in[6];
  const float* v_b       = (const float*)d_in[7];
  const float* in_proj_w = (const float*)d_in[8];
  const float* in_proj_b = (const float*)d_in[9];
  const float* mha_w     = (const float*)d_in[10];
  const float* mha_b     = (const float*)d_in[11];
  const float* out_w     = (const float*)d_in[12];
  const float* out_b     = (const float*)d_in[13];

  char* ws = (char*)d_ws;
  size_t off = 0;
  auto alloc = [&](size_t bytes) {
    char* p = ws + off;
    off += (bytes + 255) & ~(size_t)255;
    return p;
  };

  const size_t TS = (size_t)MROWS * W_DIM;

  float* tab = (float*)alloc((size_t)S_LEN * 512 * 2 * sizeof(float));
  float* maskP = (float*)alloc((size_t)128 * 128 * sizeof(float));
  u16* Xbf   = (u16*)alloc(TS * 2);                          // reused as O1
  u16* qkv1  = (u16*)alloc((size_t)MROWS * 2048 * 2);        // q,k after GEMM1+rope
  u16* qkv2  = (u16*)alloc(TS * 3 * 2);                      // q,k,v head layout
  u16* WC1   = (u16*)alloc((size_t)2048 * 1024 * 2);         // [q_w;k_w] bf16
  u16* W2    = (u16*)alloc((size_t)3072 * 1024 * 2);         // in_proj bf16
  u16* WvT   = (u16*)alloc((size_t)1024 * 1024 * 2);
  u16* WmT   = (u16*)alloc((size_t)1024 * 1024 * 2);
  u16* WO    = (u16*)alloc((size_t)1024 * 1024 * 2);
  u16* WVf   = (u16*)alloc((size_t)1024 * 1024 * 2);         // Wv2 @ Wv
  u16* WFf   = (u16*)alloc((size_t)1024 * 1024 * 2);         // Wo @ Wm
  float* bc1 = (float*)alloc(2048 * sizeof(float));
  float* bvf = (float*)alloc(1024 * sizeof(float));
  float* bff = (float*)alloc(1024 * sizeof(float));
  float* zb  = (float*)alloc(1024 * sizeof(float));
  u16* O1 = Xbf;  // X dead after GEMM_v

  // ---- prep / converts ----
  k_rope_tab<<<dim3((S_LEN * 512 + 255) / 256), 256, 0, stream>>>(tab);
  k_maskpad<<<dim3(64), 256, 0, stream>>>(mask, maskP);
  k_cvt<<<dim3(MROWS * W_DIM / 4 / 256), 256, 0, stream>>>(tensor, Xbf, MROWS * W_DIM / 4);
  k_cvt<<<dim3(1024), 256, 0, stream>>>(q_w, WC1, 262144);
  k_cvt<<<dim3(1024), 256, 0, stream>>>(k_w, WC1 + 1048576, 262144);
  k_cvt<<<dim3(3072), 256, 0, stream>>>(in_proj_w, W2, 786432);
  k_cvt<<<dim3(1024), 256, 0, stream>>>(out_w, WO, 262144);
  k_cvt_t<<<dim3(32, 32), dim3(32, 8), 0, stream>>>(v_w, WvT);
  k_cvt_t<<<dim3(32, 32), dim3(32, 8), 0, stream>>>(mha_w, WmT);
  k_bias2<<<dim3(8), 256, 0, stream>>>(q_b, k_b, bc1);
  k_zero<<<dim3(4), 256, 0, stream>>>(zb, 1024);
  k_biasfold<<<dim3(256), 256, 0, stream>>>(in_proj_w + (size_t)2048 * 1024, v_b,
                                            in_proj_b + 2048, bvf);
  k_biasfold<<<dim3(256), 256, 0, stream>>>(out_w, mha_b, out_b, bff);

  // ---- weight folds (1024^3 bf16 GEMMs, small kernel) ----
  k_gemm<0><<<dim3(8, 8), 256, 0, stream>>>(
      W2 + (size_t)2048 * 1024, 1024, WvT, zb, WVf, 1024, 1024);
  k_gemm<0><<<dim3(8, 8), 256, 0, stream>>>(
      WO, 1024, WmT, zb, WFf, 1024, 1024);

  // ---- GEMM1 + fused rope: X @ [q_w;k_w]^T + bias -> qkv1 (24832 x 2048) ----
  k_gemm256<3, 0><<<dim3(97 * 8), 512, 0, stream>>>(
      Xbf, W_DIM, WC1, bc1, qkv1, 2048, 0, tab, 8);

  // ---- v path (folded): X @ WVf^T + bvf -> v heads ----
  k_gemm256<1, 0><<<dim3(97 * 4), 512, 0, stream>>>(
      Xbf, W_DIM, WVf, bvf, qkv2 + 2 * TS, 0, TS, nullptr, 4);

  // ---- GEMM2 (block-diagonal): qkv1 @ [Wq2;Wk2]^T + b -> q,k heads (q scaled 1/8) ----
  k_gemm256<1, 1, 1><<<dim3(97 * 8), 512, 0, stream>>>(
      qkv1, 2048, W2, in_proj_b, qkv2, 0, TS, nullptr, 8);

  // ---- attention ----
  k_attn<<<dim3(B_DIM * NH), 512, 0, stream>>>(qkv2, maskP, O1);

  // ---- output (folded): O1 @ WFf^T + bff -> d_out (fp32) ----
  k_gemm256<2, 0><<<dim3(97 * 4), 512, 0, stream>>>(
      O1, W_DIM, WFf, bff, d_out, W_DIM, 0, nullptr, 4);
}